// Round 3
// baseline (725.401 us; speedup 1.0000x reference)
//
#include <hip/hip_runtime.h>

static constexpr int KA        = 256;    // dictionary atoms
static constexpr int PIX       = 1024;   // M*M
static constexpr int NBLK      = 512;    // grid blocks (co-resident, 2/CU)
static constexpr int ROWS      = 8;      // batch rows per block
static constexpr int NTHR      = 256;
static constexpr int MAX_ITERS = 2048;   // safety cap
static constexpr float LR2     = 0.2f;   // 2 * R_LR
static constexpr float LMDA_C  = 0.005f;
static constexpr float TOL2    = 1e-4f;  // TOL^2

#define AT_LOAD(p)  __hip_atomic_load((p), __ATOMIC_RELAXED, __HIP_MEMORY_SCOPE_AGENT)
#define AT_STORE(p, v) __hip_atomic_store((p), (v), __ATOMIC_RELAXED, __HIP_MEMORY_SCOPE_AGENT)

// ---------- U [1024x256] -> Ut [256x1024]  (+ zero the barrier flags) ----------
__global__ __launch_bounds__(256) void k_transpose(const float* __restrict__ U,
                                                   float* __restrict__ Ut,
                                                   int* __restrict__ flags) {
    const int g = blockIdx.x * 256 + threadIdx.x;
    if (g < NBLK) flags[g] = 0;

    __shared__ float tile[64 * 65];
    const int bx = blockIdx.x & 3;   // k-tile
    const int by = blockIdx.x >> 2;  // m-tile
    const int lane = threadIdx.x & 63;
    const int w = threadIdx.x >> 6;
    const int m0 = by * 64, k0 = bx * 64;
    #pragma unroll
    for (int i = 0; i < 16; ++i) {
        const int ml = w * 16 + i;
        tile[lane * 65 + ml] = U[(m0 + ml) * KA + k0 + lane];
    }
    __syncthreads();
    #pragma unroll
    for (int i = 0; i < 16; ++i) {
        const int kl = w * 16 + i;
        Ut[(k0 + kl) * PIX + m0 + lane] = tile[kl * 65 + lane];
    }
}

// ---------- S = U^T U : block i computes row i ----------
__global__ __launch_bounds__(256) void k_gram(const float* __restrict__ U,
                                              const float* __restrict__ Ut,
                                              float* __restrict__ S) {
    __shared__ float col[PIX];
    const int i = blockIdx.x;
    const int t = threadIdx.x;
    #pragma unroll
    for (int q = 0; q < 4; ++q) col[t + 256 * q] = Ut[i * PIX + t + 256 * q];
    __syncthreads();
    float acc = 0.f;
    for (int p = 0; p < PIX; p += 4) {
        float4 cv = *(const float4*)&col[p];
        acc += cv.x * U[(p + 0) * KA + t];
        acc += cv.y * U[(p + 1) * KA + t];
        acc += cv.z * U[(p + 2) * KA + t];
        acc += cv.w * U[(p + 3) * KA + t];
    }
    S[i * KA + t] = acc;
}

// ---------- persistent ISTA, lag-2 run-ahead decision ----------
// thread t: c = t&63 -> cols 4c..4c+3 ; rg = t>>6 -> j-slice [64rg,64rg+64)
// final ownership: rows 2rg, 2rg+1  x  cols 4c..4c+3
__global__ __launch_bounds__(NTHR, 2) void k_ista(const float* __restrict__ img,
                                                  const float* __restrict__ U,
                                                  const float* __restrict__ S,
                                                  const float* __restrict__ Ut,
                                                  float* __restrict__ out,
                                                  float* partials, int* flags) {
    __shared__ float part[4 * ROWS * KA];  // 32 KB: imgT in prologue, split-j partials after
    __shared__ float Rsh[KA * ROWS];       // 8 KB, layout [k][b]
    __shared__ float red[12];

    const int t = threadIdx.x;
    const int c = t & 63;
    const int rg = t >> 6;
    const int blk = blockIdx.x;
    const int row0 = blk * ROWS;

    // ---- stage img rows transposed into part ([p][b], stride 8) ----
    #pragma unroll
    for (int b = 0; b < ROWS; ++b) {
        const float* src = img + (size_t)(row0 + b) * PIX;
        #pragma unroll
        for (int q = 0; q < 4; ++q) {
            const int p = t + 256 * q;
            part[p * ROWS + b] = src[p];
        }
    }
    __syncthreads();

    // ---- G = img @ U, split over p (each rg owns 256 of 1024) ----
    float Ga[8][4];
    #pragma unroll
    for (int b = 0; b < 8; ++b)
        #pragma unroll
        for (int i = 0; i < 4; ++i) Ga[b][i] = 0.f;
    {
        const float* Up = U + (size_t)(rg * 256) * KA + (c << 2);
        const float* Ip = part + rg * 256 * ROWS;
        #pragma unroll 4
        for (int p = 0; p < 256; ++p) {
            float4 r0 = *(const float4*)&Ip[p * ROWS];
            float4 r1 = *(const float4*)&Ip[p * ROWS + 4];
            float4 uv = *(const float4*)&Up[(size_t)p * KA];
            Ga[0][0] += r0.x * uv.x; Ga[0][1] += r0.x * uv.y; Ga[0][2] += r0.x * uv.z; Ga[0][3] += r0.x * uv.w;
            Ga[1][0] += r0.y * uv.x; Ga[1][1] += r0.y * uv.y; Ga[1][2] += r0.y * uv.z; Ga[1][3] += r0.y * uv.w;
            Ga[2][0] += r0.z * uv.x; Ga[2][1] += r0.z * uv.y; Ga[2][2] += r0.z * uv.z; Ga[2][3] += r0.z * uv.w;
            Ga[3][0] += r0.w * uv.x; Ga[3][1] += r0.w * uv.y; Ga[3][2] += r0.w * uv.z; Ga[3][3] += r0.w * uv.w;
            Ga[4][0] += r1.x * uv.x; Ga[4][1] += r1.x * uv.y; Ga[4][2] += r1.x * uv.z; Ga[4][3] += r1.x * uv.w;
            Ga[5][0] += r1.y * uv.x; Ga[5][1] += r1.y * uv.y; Ga[5][2] += r1.y * uv.z; Ga[5][3] += r1.y * uv.w;
            Ga[6][0] += r1.z * uv.x; Ga[6][1] += r1.z * uv.y; Ga[6][2] += r1.z * uv.z; Ga[6][3] += r1.z * uv.w;
            Ga[7][0] += r1.w * uv.x; Ga[7][1] += r1.w * uv.y; Ga[7][2] += r1.w * uv.z; Ga[7][3] += r1.w * uv.w;
        }
    }
    __syncthreads();  // done reading imgT from part
    {
        float* pw = part + rg * (ROWS * KA) + (c << 2);
        #pragma unroll
        for (int b = 0; b < 8; ++b)
            *(float4*)&pw[b * KA] = make_float4(Ga[b][0], Ga[b][1], Ga[b][2], Ga[b][3]);
    }
    __syncthreads();
    float G0[4], G1[4];
    {
        #pragma unroll
        for (int i = 0; i < 4; ++i) { G0[i] = 0.f; G1[i] = 0.f; }
        const float* pr = part + (rg << 1) * KA + (c << 2);
        #pragma unroll
        for (int rr = 0; rr < 4; ++rr) {
            float4 v0 = *(const float4*)&pr[rr * (ROWS * KA)];
            float4 v1 = *(const float4*)&pr[rr * (ROWS * KA) + KA];
            G0[0] += v0.x; G0[1] += v0.y; G0[2] += v0.z; G0[3] += v0.w;
            G1[0] += v1.x; G1[1] += v1.y; G1[2] += v1.z; G1[3] += v1.w;
        }
    }

    // ---- R = 0, snapshot = 0 ----
    float R0[4] = {0.f, 0.f, 0.f, 0.f}, R1[4] = {0.f, 0.f, 0.f, 0.f};
    float s0[4] = {0.f, 0.f, 0.f, 0.f}, s1[4] = {0.f, 0.f, 0.f, 0.f};  // R_{iter-1}
    #pragma unroll
    for (int q = 0; q < 8; ++q) Rsh[t + 256 * q] = 0.f;
    if (t == 0) red[8] = 0.f;
    __syncthreads();

    bool fired = false;

    // ---- ISTA loop: iter computes R_{iter+1}; consumes global decision for iter-2 ----
    for (int iter = 0; iter < MAX_ITERS; ++iter) {
        // top: wave 0 verifies all blocks posted iter-2, then issues the 512-partial
        // loads; their L3 latency drains behind the dot loop below.
        float gn[8], gd[8];
        const bool chk = (iter >= 2) && (t < 64);
        if (chk) {
            const int want = iter - 1;  // flag >= iter-1  <=>  posted iter-2
            #pragma unroll
            for (int q = 0; q < 8; ++q) {
                while (AT_LOAD(&flags[t * 8 + q]) < want)
                    __builtin_amdgcn_s_sleep(1);
            }
            asm volatile("" ::: "memory");  // no hoisting loads above the spin
            const float* ps = partials + (size_t)((iter - 2) & 3) * (2 * NBLK);
            #pragma unroll
            for (int q = 0; q < 8; ++q) {
                gn[q] = AT_LOAD(&ps[(t * 8 + q) * 2 + 0]);
                gd[q] = AT_LOAD(&ps[(t * 8 + q) * 2 + 1]);
            }
        }

        // split-j dot: a[b][i] partial over j in [64rg, 64rg+64)
        float a[8][4];
        #pragma unroll
        for (int b = 0; b < 8; ++b)
            #pragma unroll
            for (int i = 0; i < 4; ++i) a[b][i] = 0.f;
        {
            const float* Sp = S + (size_t)(rg * 64) * KA + (c << 2);
            const float* Rp = Rsh + rg * 64 * ROWS;
            #pragma unroll 8
            for (int jj = 0; jj < 64; ++jj) {
                float4 r0 = *(const float4*)&Rp[jj * ROWS];
                float4 r1 = *(const float4*)&Rp[jj * ROWS + 4];
                float4 sv = *(const float4*)&Sp[(size_t)jj * KA];
                a[0][0] += r0.x * sv.x; a[0][1] += r0.x * sv.y; a[0][2] += r0.x * sv.z; a[0][3] += r0.x * sv.w;
                a[1][0] += r0.y * sv.x; a[1][1] += r0.y * sv.y; a[1][2] += r0.y * sv.z; a[1][3] += r0.y * sv.w;
                a[2][0] += r0.z * sv.x; a[2][1] += r0.z * sv.y; a[2][2] += r0.z * sv.z; a[2][3] += r0.z * sv.w;
                a[3][0] += r0.w * sv.x; a[3][1] += r0.w * sv.y; a[3][2] += r0.w * sv.z; a[3][3] += r0.w * sv.w;
                a[4][0] += r1.x * sv.x; a[4][1] += r1.x * sv.y; a[4][2] += r1.x * sv.z; a[4][3] += r1.x * sv.w;
                a[5][0] += r1.y * sv.x; a[5][1] += r1.y * sv.y; a[5][2] += r1.y * sv.z; a[5][3] += r1.y * sv.w;
                a[6][0] += r1.z * sv.x; a[6][1] += r1.z * sv.y; a[6][2] += r1.z * sv.z; a[6][3] += r1.z * sv.w;
                a[7][0] += r1.w * sv.x; a[7][1] += r1.w * sv.y; a[7][2] += r1.w * sv.z; a[7][3] += r1.w * sv.w;
            }
        }
        {
            float* pw = part + rg * (ROWS * KA) + (c << 2);
            #pragma unroll
            for (int b = 0; b < 8; ++b)
                *(float4*)&pw[b * KA] = make_float4(a[b][0], a[b][1], a[b][2], a[b][3]);
        }
        __syncthreads();  // S1: partials visible; all Rsh dot-reads complete

        float a0[4] = {0.f, 0.f, 0.f, 0.f}, a1[4] = {0.f, 0.f, 0.f, 0.f};
        {
            const float* pr = part + (rg << 1) * KA + (c << 2);
            #pragma unroll
            for (int rr = 0; rr < 4; ++rr) {
                float4 v0 = *(const float4*)&pr[rr * (ROWS * KA)];
                float4 v1 = *(const float4*)&pr[rr * (ROWS * KA) + KA];
                a0[0] += v0.x; a0[1] += v0.y; a0[2] += v0.z; a0[3] += v0.w;
                a1[0] += v1.x; a1[1] += v1.y; a1[2] += v1.z; a1[3] += v1.w;
            }
        }

        // update -> R_{iter+1} in N0/N1; num/den for ratio_iter; publish to Rsh
        float num = 0.f, den = 0.f;
        float N0[4], N1[4];
        #pragma unroll
        for (int i = 0; i < 4; ++i) {
            const float v0 = R0[i] + LR2 * (G0[i] - a0[i]);
            const float v1 = R1[i] + LR2 * (G1[i] - a1[i]);
            const float n0 = fmaxf(v0 - LMDA_C, 0.f) - fmaxf(-v0 - LMDA_C, 0.f);
            const float n1 = fmaxf(v1 - LMDA_C, 0.f) - fmaxf(-v1 - LMDA_C, 0.f);
            const float d0 = n0 - R0[i], d1 = n1 - R1[i];
            num += d0 * d0 + d1 * d1;
            den += R0[i] * R0[i] + R1[i] * R1[i];
            N0[i] = n0; N1[i] = n1;
            *(float2*)&Rsh[((c << 2) + i) * ROWS + (rg << 1)] = make_float2(n0, n1);
        }

        // wave reduce num/den -> red[]
        #pragma unroll
        for (int off = 32; off > 0; off >>= 1) {
            num += __shfl_down(num, off, 64);
            den += __shfl_down(den, off, 64);
        }
        if (c == 0) { red[rg * 2] = num; red[rg * 2 + 1] = den; }

        // global decision for iter-2 (identical reduce order in every block)
        if (chk) {
            float n = gn[0] + gn[1] + gn[2] + gn[3] + gn[4] + gn[5] + gn[6] + gn[7];
            float d = gd[0] + gd[1] + gd[2] + gd[3] + gd[4] + gd[5] + gd[6] + gd[7];
            #pragma unroll
            for (int off = 32; off > 0; off >>= 1) {
                n += __shfl_down(n, off, 64);
                d += __shfl_down(d, off, 64);
            }
            if (t == 0) red[8] = (n < TOL2 * d) ? 1.f : 0.f;
        }
        __syncthreads();  // S2: Rsh(R_{iter+1}), red[0..7], red[8] all visible

        // post this iter's block partial (non-blocking; consumed 2 iters later)
        if (t == 0) {
            const float n = red[0] + red[2] + red[4] + red[6];
            const float d = red[1] + red[3] + red[5] + red[7];
            float* pd = partials + (size_t)(iter & 3) * (2 * NBLK) + blk * 2;
            AT_STORE(&pd[0], n);
            AT_STORE(&pd[1], d);
            __builtin_amdgcn_s_waitcnt(0);  // stores at coherence point before flag bump
            __hip_atomic_fetch_add(&flags[blk], 1, __ATOMIC_RELAXED, __HIP_MEMORY_SCOPE_AGENT);
        }

        if (red[8] != 0.f) { fired = true; break; }  // ratio_{iter-2} < TOL -> output R_{iter-1}

        // rotate: snapshot <- R_iter, R <- R_{iter+1}
        #pragma unroll
        for (int i = 0; i < 4; ++i) { s0[i] = R0[i]; s1[i] = R1[i]; R0[i] = N0[i]; R1[i] = N1[i]; }
    }

    // ---- restore the converged iterate into Rsh ----
    #pragma unroll
    for (int i = 0; i < 4; ++i) {
        float2 v;
        v.x = fired ? s0[i] : R0[i];
        v.y = fired ? s1[i] : R1[i];
        *(float2*)&Rsh[((c << 2) + i) * ROWS + (rg << 1)] = v;
    }
    __syncthreads();

    // ---- out = R @ U^T ----
    #pragma unroll
    for (int q = 0; q < 4; ++q) {
        float p0[4] = {0.f, 0.f, 0.f, 0.f}, p1[4] = {0.f, 0.f, 0.f, 0.f};
        const float* Utp = Ut + q * 256 + (c << 2);
        #pragma unroll 4
        for (int k = 0; k < KA; ++k) {
            float2 rv = *(const float2*)&Rsh[k * ROWS + (rg << 1)];
            float4 uv = *(const float4*)&Utp[(size_t)k * PIX];
            p0[0] += rv.x * uv.x; p0[1] += rv.x * uv.y; p0[2] += rv.x * uv.z; p0[3] += rv.x * uv.w;
            p1[0] += rv.y * uv.x; p1[1] += rv.y * uv.y; p1[2] += rv.y * uv.z; p1[3] += rv.y * uv.w;
        }
        const size_t o0 = (size_t)(row0 + (rg << 1) + 0) * PIX + q * 256 + (c << 2);
        const size_t o1 = (size_t)(row0 + (rg << 1) + 1) * PIX + q * 256 + (c << 2);
        *(float4*)&out[o0] = make_float4(p0[0], p0[1], p0[2], p0[3]);
        *(float4*)&out[o1] = make_float4(p1[0], p1[1], p1[2], p1[3]);
    }
}

extern "C" void kernel_launch(void* const* d_in, const int* in_sizes, int n_in,
                              void* d_out, int out_size, void* d_ws, size_t ws_size,
                              hipStream_t stream) {
    const float* img = (const float*)d_in[0];  // [4096, 1024]
    const float* U   = (const float*)d_in[1];  // [1024, 256]
    float* out = (float*)d_out;                // [4096, 1024]
    float* ws  = (float*)d_ws;

    float* Ut       = ws;                        // 262144 floats
    float* S        = ws + 262144;               // 65536 floats
    float* partials = ws + 262144 + 65536;       // 4 slots * 2 * NBLK = 4096 floats
    int*   flags    = (int*)(ws + 262144 + 65536 + 4096);  // NBLK ints

    k_transpose<<<64, 256, 0, stream>>>(U, Ut, flags);
    k_gram<<<256, 256, 0, stream>>>(U, Ut, S);

    void* args[] = {(void*)&img, (void*)&U, (void*)&S, (void*)&Ut,
                    (void*)&out, (void*)&partials, (void*)&flags};
    hipLaunchCooperativeKernel((void*)k_ista, dim3(NBLK), dim3(NTHR), args, 0, stream);
}

// Round 4
// 553.307 us; speedup vs baseline: 1.3110x; 1.3110x over previous
//
#include <hip/hip_runtime.h>

static constexpr int KA        = 256;    // dictionary atoms
static constexpr int PIX       = 1024;   // M*M
static constexpr int NBLK      = 256;    // cooperative blocks (1/CU)
static constexpr int NTHR      = 1024;   // 16 waves
static constexpr int ROWS      = 16;     // batch rows per block
static constexpr int MAX_ITERS = 2048;
static constexpr float LR2     = 0.2f;   // 2 * R_LR
static constexpr float LMDA_C  = 0.005f;
static constexpr float TOL2    = 1e-4f;  // TOL^2

#define AT_LOAD(p)     __hip_atomic_load((p), __ATOMIC_RELAXED, __HIP_MEMORY_SCOPE_AGENT)
#define AT_STORE(p, v) __hip_atomic_store((p), (v), __ATOMIC_RELAXED, __HIP_MEMORY_SCOPE_AGENT)

// ---------- U [1024x256] -> Ut [256x1024]  (+ zero the barrier flags) ----------
__global__ __launch_bounds__(256) void k_transpose(const float* __restrict__ U,
                                                   float* __restrict__ Ut,
                                                   int* __restrict__ flags) {
    const int g = blockIdx.x * 256 + threadIdx.x;
    if (g < NBLK) flags[g] = 0;

    __shared__ float tile[64 * 65];
    const int bx = blockIdx.x & 3;   // k-tile
    const int by = blockIdx.x >> 2;  // m-tile
    const int lane = threadIdx.x & 63;
    const int w = threadIdx.x >> 6;
    const int m0 = by * 64, k0 = bx * 64;
    #pragma unroll
    for (int i = 0; i < 16; ++i) {
        const int ml = w * 16 + i;
        tile[lane * 65 + ml] = U[(m0 + ml) * KA + k0 + lane];
    }
    __syncthreads();
    #pragma unroll
    for (int i = 0; i < 16; ++i) {
        const int kl = w * 16 + i;
        Ut[(k0 + kl) * PIX + m0 + lane] = tile[kl * 65 + lane];
    }
}

// ---------- S = U^T U : block i computes row i ----------
__global__ __launch_bounds__(256) void k_gram(const float* __restrict__ U,
                                              const float* __restrict__ Ut,
                                              float* __restrict__ S) {
    __shared__ float col[PIX];
    const int i = blockIdx.x;
    const int t = threadIdx.x;
    #pragma unroll
    for (int q = 0; q < 4; ++q) col[t + 256 * q] = Ut[i * PIX + t + 256 * q];
    __syncthreads();
    float acc = 0.f;
    for (int p = 0; p < PIX; p += 4) {
        float4 cv = *(const float4*)&col[p];
        acc += cv.x * U[(p + 0) * KA + t];
        acc += cv.y * U[(p + 1) * KA + t];
        acc += cv.z * U[(p + 2) * KA + t];
        acc += cv.w * U[(p + 3) * KA + t];
    }
    S[i * KA + t] = acc;
}

// ---------- G = img @ U : 256 blocks x 512 thr, 16-row tiles ----------
__global__ __launch_bounds__(512) void k_gemmG(const float* __restrict__ img,
                                               const float* __restrict__ U,
                                               float* __restrict__ G) {
    __shared__ float Ush[32 * KA];  // 32 KB
    const int t = threadIdx.x;
    const int rw = t >> 6;              // rows rw, rw+8 (wave-uniform)
    const int c4 = (t & 63) << 2;
    const int row0 = blockIdx.x * 16;
    float a0[4] = {0.f, 0.f, 0.f, 0.f}, a1[4] = {0.f, 0.f, 0.f, 0.f};
    for (int kc = 0; kc < 32; ++kc) {
        const int k0 = kc << 5;
        {   // stage U[k0..k0+31][0..255]
            const int kk = t >> 4;          // 0..31
            const int cc = (t & 15) << 4;   // step 16
            #pragma unroll
            for (int i = 0; i < 4; ++i)
                *(float4*)&Ush[kk * KA + cc + (i << 2)] =
                    *(const float4*)&U[(size_t)(k0 + kk) * KA + cc + (i << 2)];
        }
        __syncthreads();
        const float* i0 = &img[(size_t)(row0 + rw) * PIX + k0];
        const float* i1 = &img[(size_t)(row0 + rw + 8) * PIX + k0];
        #pragma unroll 8
        for (int k = 0; k < 32; ++k) {
            const float r0 = i0[k], r1 = i1[k];   // wave-uniform -> L1 broadcast
            const float4 uv = *(const float4*)&Ush[k * KA + c4];
            a0[0] += r0 * uv.x; a0[1] += r0 * uv.y; a0[2] += r0 * uv.z; a0[3] += r0 * uv.w;
            a1[0] += r1 * uv.x; a1[1] += r1 * uv.y; a1[2] += r1 * uv.z; a1[3] += r1 * uv.w;
        }
        __syncthreads();
    }
    *(float4*)&G[(size_t)(row0 + rw) * KA + c4]     = make_float4(a0[0], a0[1], a0[2], a0[3]);
    *(float4*)&G[(size_t)(row0 + rw + 8) * KA + c4] = make_float4(a1[0], a1[1], a1[2], a1[3]);
}

// ---------- out = R @ Ut : 256 blocks x 512 thr, 16-row tiles ----------
__global__ __launch_bounds__(512) void k_out(const float* __restrict__ Rws,
                                             const float* __restrict__ Ut,
                                             float* __restrict__ out) {
    __shared__ float Ush[8 * PIX];  // 32 KB
    const int t = threadIdx.x;
    const int rw = t >> 6;               // rows rw, rw+8 (wave-uniform)
    const int c16 = (t & 63) << 4;
    const int row0 = blockIdx.x * 16;
    float a0[16], a1[16];
    #pragma unroll
    for (int i = 0; i < 16; ++i) { a0[i] = 0.f; a1[i] = 0.f; }
    for (int kc = 0; kc < 32; ++kc) {
        const int k0 = kc << 3;
        {   // stage Ut[k0..k0+7][0..1023]
            const int kk = t >> 6;          // 0..7
            const int cc = (t & 63) << 4;   // 16 dwords/thread
            #pragma unroll
            for (int i = 0; i < 4; ++i)
                *(float4*)&Ush[kk * PIX + cc + (i << 2)] =
                    *(const float4*)&Ut[(size_t)(k0 + kk) * PIX + cc + (i << 2)];
        }
        __syncthreads();
        const float* rp0 = &Rws[(size_t)(row0 + rw) * KA + k0];
        const float* rp1 = &Rws[(size_t)(row0 + rw + 8) * KA + k0];
        #pragma unroll
        for (int k = 0; k < 8; ++k) {
            const float r0 = rp0[k], r1 = rp1[k];  // wave-uniform
            #pragma unroll
            for (int g = 0; g < 4; ++g) {
                const float4 uv = *(const float4*)&Ush[k * PIX + c16 + (g << 2)];
                a0[g * 4 + 0] += r0 * uv.x; a0[g * 4 + 1] += r0 * uv.y;
                a0[g * 4 + 2] += r0 * uv.z; a0[g * 4 + 3] += r0 * uv.w;
                a1[g * 4 + 0] += r1 * uv.x; a1[g * 4 + 1] += r1 * uv.y;
                a1[g * 4 + 2] += r1 * uv.z; a1[g * 4 + 3] += r1 * uv.w;
            }
        }
        __syncthreads();
    }
    #pragma unroll
    for (int g = 0; g < 4; ++g) {
        *(float4*)&out[(size_t)(row0 + rw) * PIX + c16 + (g << 2)] =
            make_float4(a0[g * 4], a0[g * 4 + 1], a0[g * 4 + 2], a0[g * 4 + 3]);
        *(float4*)&out[(size_t)(row0 + rw + 8) * PIX + c16 + (g << 2)] =
            make_float4(a1[g * 4], a1[g * 4 + 1], a1[g * 4 + 2], a1[g * 4 + 3]);
    }
}

// ---------- persistent ISTA: S lives in registers ----------
// dot phase : p2 = t&127 -> cols {2p2, 2p2+1}; sl = t>>7 -> j in [32*sl, 32*sl+32)
// owner     : b_o = t>>6 (row), c4 = (t&63)*4 (4 cols)
__global__ __launch_bounds__(NTHR, 1) void k_ista(const float* __restrict__ S,
                                                  const float* __restrict__ G,
                                                  float* __restrict__ Rws,
                                                  float* partials, int* flags) {
    __shared__ float buf[4 * 256 * 9];   // 36.9 KB: cross-slice partials (4-row chunks)
    __shared__ float Rsh[ROWS * KA];     // 16 KB, [b][j]
    __shared__ float red[40];

    const int t = threadIdx.x;
    const int p2 = t & 127, sl = t >> 7, j0 = sl << 5;
    const int b_o = t >> 6;              // == wave id
    const int c4 = (t & 63) << 2;
    const int blk = blockIdx.x, row0 = blk * ROWS;

    // ---- load this thread's S slice into registers (iteration-invariant) ----
    float2 sreg[32];
    #pragma unroll
    for (int j = 0; j < 32; ++j)
        sreg[j] = *(const float2*)&S[(size_t)(j0 + j) * KA + (p2 << 1)];

    // ---- load G for owned outputs ----
    float Gr[4];
    {
        float4 g = *(const float4*)&G[(size_t)(row0 + b_o) * KA + c4];
        Gr[0] = g.x; Gr[1] = g.y; Gr[2] = g.z; Gr[3] = g.w;
    }

    // ---- R = 0 ----
    float Rold[4] = {0.f, 0.f, 0.f, 0.f}, snap[4] = {0.f, 0.f, 0.f, 0.f};
    *(float4*)&Rsh[t << 2] = make_float4(0.f, 0.f, 0.f, 0.f);
    if (t == 0) red[36] = 0.f;
    __syncthreads();

    bool fired = false;

    for (int iter = 0; iter < MAX_ITERS; ++iter) {
        // run-ahead: wave 0 confirms all blocks posted iter-2, sums their partials
        float gsn = 0.f, gsd = 0.f;
        const bool chk = (iter >= 2) && (t < 64);
        if (chk) {
            const int want = iter - 1;  // flag >= iter-1 <=> posted iter-2
            #pragma unroll
            for (int q = 0; q < 4; ++q)
                while (AT_LOAD(&flags[t + (q << 6)]) < want) __builtin_amdgcn_s_sleep(1);
            asm volatile("" ::: "memory");
            const float* ps = partials + (size_t)((iter - 2) & 3) * (2 * NBLK);
            #pragma unroll
            for (int q = 0; q < 4; ++q) {
                gsn += AT_LOAD(&ps[(t + (q << 6)) * 2 + 0]);
                gsd += AT_LOAD(&ps[(t + (q << 6)) * 2 + 1]);
            }
        }

        float num = 0.f, den = 0.f;
        float Nnew[4];

        // ---- 4 chunks of 4 rows: register-S dot + LDS cross-slice reduce ----
        for (int cc = 0; cc < 4; ++cc) {
            float a00 = 0.f, a01 = 0.f, a10 = 0.f, a11 = 0.f;
            float a20 = 0.f, a21 = 0.f, a30 = 0.f, a31 = 0.f;
            const float* Rp = &Rsh[(cc << 2) * KA + j0];
            #pragma unroll
            for (int q = 0; q < 8; ++q) {
                const float4 r0 = *(const float4*)&Rp[0 * KA + (q << 2)];  // broadcast
                const float4 r1 = *(const float4*)&Rp[1 * KA + (q << 2)];
                const float4 r2 = *(const float4*)&Rp[2 * KA + (q << 2)];
                const float4 r3 = *(const float4*)&Rp[3 * KA + (q << 2)];
                #define ISTA_STEP(JJ, X0, X1, X2, X3)                         \
                    { const float2 sv = sreg[(q << 2) + JJ];                  \
                      a00 += (X0) * sv.x; a01 += (X0) * sv.y;                 \
                      a10 += (X1) * sv.x; a11 += (X1) * sv.y;                 \
                      a20 += (X2) * sv.x; a21 += (X2) * sv.y;                 \
                      a30 += (X3) * sv.x; a31 += (X3) * sv.y; }
                ISTA_STEP(0, r0.x, r1.x, r2.x, r3.x)
                ISTA_STEP(1, r0.y, r1.y, r2.y, r3.y)
                ISTA_STEP(2, r0.z, r1.z, r2.z, r3.z)
                ISTA_STEP(3, r0.w, r1.w, r2.w, r3.w)
                #undef ISTA_STEP
            }
            __syncthreads();  // A: prior reduce-reads of buf complete
            {
                const int cA = p2 << 1;
                buf[((0 << 8) + cA) * 9 + sl] = a00; buf[((0 << 8) + cA + 1) * 9 + sl] = a01;
                buf[((1 << 8) + cA) * 9 + sl] = a10; buf[((1 << 8) + cA + 1) * 9 + sl] = a11;
                buf[((2 << 8) + cA) * 9 + sl] = a20; buf[((2 << 8) + cA + 1) * 9 + sl] = a21;
                buf[((3 << 8) + cA) * 9 + sl] = a30; buf[((3 << 8) + cA + 1) * 9 + sl] = a31;
            }
            __syncthreads();  // B: partials visible
            if ((b_o >> 2) == cc) {
                const int rr = b_o & 3;
                #pragma unroll
                for (int i = 0; i < 4; ++i) {
                    const float* pb = &buf[((rr << 8) + c4 + i) * 9];
                    const float av = ((pb[0] + pb[1]) + (pb[2] + pb[3])) +
                                     ((pb[4] + pb[5]) + (pb[6] + pb[7]));
                    const float v = Rold[i] + LR2 * (Gr[i] - av);
                    const float n = fmaxf(v - LMDA_C, 0.f) - fmaxf(-v - LMDA_C, 0.f);
                    const float d = n - Rold[i];
                    num += d * d; den += Rold[i] * Rold[i];
                    Nnew[i] = n;
                }
                *(float4*)&Rsh[b_o * KA + c4] = make_float4(Nnew[0], Nnew[1], Nnew[2], Nnew[3]);
            }
        }

        // ---- block reduce num/den ----
        #pragma unroll
        for (int off = 32; off > 0; off >>= 1) {
            num += __shfl_down(num, off, 64);
            den += __shfl_down(den, off, 64);
        }
        if ((t & 63) == 0) { red[(t >> 6) * 2] = num; red[(t >> 6) * 2 + 1] = den; }
        __syncthreads();  // C
        if (t == 0) {
            float n = 0.f, d = 0.f;
            #pragma unroll
            for (int i = 0; i < 16; ++i) { n += red[2 * i]; d += red[2 * i + 1]; }
            float* pd = partials + (size_t)(iter & 3) * (2 * NBLK) + blk * 2;
            AT_STORE(&pd[0], n);   // fire-and-forget; flag bump comes after sync D
            AT_STORE(&pd[1], d);
        }
        if (chk) {  // global decision for iter-2, identical order in every block
            float n = gsn, d = gsd;
            #pragma unroll
            for (int off = 32; off > 0; off >>= 1) {
                n += __shfl_down(n, off, 64);
                d += __shfl_down(d, off, 64);
            }
            if (t == 0) red[36] = (n < TOL2 * d) ? 1.f : 0.f;
        }
        __syncthreads();  // D
        if (t == 0) {
            __builtin_amdgcn_s_waitcnt(0);  // stores drained during decision phase -> cheap
            __hip_atomic_fetch_add(&flags[blk], 1, __ATOMIC_RELAXED, __HIP_MEMORY_SCOPE_AGENT);
        }
        if (red[36] != 0.f) { fired = true; break; }
        #pragma unroll
        for (int i = 0; i < 4; ++i) { snap[i] = Rold[i]; Rold[i] = Nnew[i]; }
    }

    // ---- store converged iterate (reference returns R_{iter-1} when fired) ----
    {
        float4 v;
        v.x = fired ? snap[0] : Rold[0];
        v.y = fired ? snap[1] : Rold[1];
        v.z = fired ? snap[2] : Rold[2];
        v.w = fired ? snap[3] : Rold[3];
        *(float4*)&Rws[(size_t)(row0 + b_o) * KA + c4] = v;
    }
}

extern "C" void kernel_launch(void* const* d_in, const int* in_sizes, int n_in,
                              void* d_out, int out_size, void* d_ws, size_t ws_size,
                              hipStream_t stream) {
    const float* img = (const float*)d_in[0];  // [4096, 1024]
    const float* U   = (const float*)d_in[1];  // [1024, 256]
    float* out = (float*)d_out;                // [4096, 1024]
    float* ws  = (float*)d_ws;

    float* Ut       = ws;                       // 262144
    float* S        = ws + 262144;              // 65536
    float* G        = ws + 327680;              // 1048576
    float* Rws      = ws + 1376256;             // 1048576
    float* partials = ws + 2424832;             // 4*2*256 = 2048
    int*   flags    = (int*)(ws + 2426880);     // 256

    k_transpose<<<64, 256, 0, stream>>>(U, Ut, flags);
    k_gram<<<256, 256, 0, stream>>>(U, Ut, S);
    k_gemmG<<<256, 512, 0, stream>>>(img, U, G);

    void* args[] = {(void*)&S, (void*)&G, (void*)&Rws, (void*)&partials, (void*)&flags};
    hipLaunchCooperativeKernel((void*)k_ista, dim3(NBLK), dim3(NTHR), args, 0, stream);

    k_out<<<256, 512, 0, stream>>>(Rws, Ut, out);
}

// Round 5
// 487.009 us; speedup vs baseline: 1.4895x; 1.1361x over previous
//
#include <hip/hip_runtime.h>

static constexpr int KA        = 256;    // dictionary atoms
static constexpr int PIX       = 1024;   // M*M
static constexpr int NBLK      = 256;    // cooperative blocks (1/CU)
static constexpr int NTHR      = 1024;   // 16 waves
static constexpr int ROWS      = 16;     // batch rows per block
static constexpr int MAX_ITERS = 2048;
static constexpr float LR2     = 0.2f;   // 2 * R_LR
static constexpr float LMDA_C  = 0.005f;
static constexpr float TOL2    = 1e-4f;  // TOL^2

#define AT_LOAD(p)     __hip_atomic_load((p), __ATOMIC_RELAXED, __HIP_MEMORY_SCOPE_AGENT)
#define AT_STORE(p, v) __hip_atomic_store((p), (v), __ATOMIC_RELAXED, __HIP_MEMORY_SCOPE_AGENT)

// ---------- U [1024x256] -> Ut [256x1024]  (+ zero the barrier flags) ----------
__global__ __launch_bounds__(256) void k_transpose(const float* __restrict__ U,
                                                   float* __restrict__ Ut,
                                                   int* __restrict__ flags) {
    const int g = blockIdx.x * 256 + threadIdx.x;
    if (g < NBLK) flags[g] = 0;

    __shared__ float tile[64 * 65];
    const int bx = blockIdx.x & 3;   // k-tile
    const int by = blockIdx.x >> 2;  // m-tile
    const int lane = threadIdx.x & 63;
    const int w = threadIdx.x >> 6;
    const int m0 = by * 64, k0 = bx * 64;
    #pragma unroll
    for (int i = 0; i < 16; ++i) {
        const int ml = w * 16 + i;
        tile[lane * 65 + ml] = U[(m0 + ml) * KA + k0 + lane];
    }
    __syncthreads();
    #pragma unroll
    for (int i = 0; i < 16; ++i) {
        const int kl = w * 16 + i;
        Ut[(k0 + kl) * PIX + m0 + lane] = tile[kl * 65 + lane];
    }
}

// ---------- S = U^T U : block i computes row i ----------
__global__ __launch_bounds__(256) void k_gram(const float* __restrict__ U,
                                              const float* __restrict__ Ut,
                                              float* __restrict__ S) {
    __shared__ float col[PIX];
    const int i = blockIdx.x;
    const int t = threadIdx.x;
    #pragma unroll
    for (int q = 0; q < 4; ++q) col[t + 256 * q] = Ut[i * PIX + t + 256 * q];
    __syncthreads();
    float acc = 0.f;
    for (int p = 0; p < PIX; p += 4) {
        float4 cv = *(const float4*)&col[p];
        acc += cv.x * U[(p + 0) * KA + t];
        acc += cv.y * U[(p + 1) * KA + t];
        acc += cv.z * U[(p + 2) * KA + t];
        acc += cv.w * U[(p + 3) * KA + t];
    }
    S[i * KA + t] = acc;
}

// ---------- G = img @ U : 512 blocks x 512 thr, 8-row tiles ----------
// thread: p2 = t&127 -> cols {2p2,2p2+1}; sl = t>>7 -> k in [sl*128,+128) of each half
__global__ __launch_bounds__(512) void k_gemmG2(const float* __restrict__ img,
                                                const float* __restrict__ U,
                                                float* __restrict__ G) {
    __shared__ float ia[8 * 512];        // 16 KB: 8 rows x half-K
    __shared__ float pbuf[4 * 8 * 260];  // 33.3 KB cross-slice partials
    const int t = threadIdx.x;
    const int p2 = t & 127, sl = t >> 7;
    const int row0 = blockIdx.x * 8;

    float g[8][2];
    #pragma unroll
    for (int r = 0; r < 8; ++r) { g[r][0] = 0.f; g[r][1] = 0.f; }

    for (int h = 0; h < 2; ++h) {
        __syncthreads();  // protect ia reuse at h=1
        {   // stage 8 rows x 512 k (coalesced b128 both sides)
            const int r = t >> 6, cc = (t & 63) << 3;
            const float* src = &img[(size_t)(row0 + r) * PIX + (h << 9) + cc];
            *(float4*)&ia[r * 512 + cc]     = *(const float4*)&src[0];
            *(float4*)&ia[r * 512 + cc + 4] = *(const float4*)&src[4];
        }
        __syncthreads();
        const int kbase = (h << 9) + (sl << 7);
        const float* Up = &U[(size_t)kbase * KA + (p2 << 1)];
        const float* ip = &ia[sl << 7];
        #pragma unroll 2
        for (int k = 0; k < 128; k += 4) {
            const float2 u0 = *(const float2*)&Up[(size_t)(k + 0) * KA];
            const float2 u1 = *(const float2*)&Up[(size_t)(k + 1) * KA];
            const float2 u2 = *(const float2*)&Up[(size_t)(k + 2) * KA];
            const float2 u3 = *(const float2*)&Up[(size_t)(k + 3) * KA];
            #pragma unroll
            for (int rr = 0; rr < 8; ++rr) {
                const float4 iv = *(const float4*)&ip[rr * 512 + k];  // broadcast
                g[rr][0] += iv.x * u0.x; g[rr][1] += iv.x * u0.y;
                g[rr][0] += iv.y * u1.x; g[rr][1] += iv.y * u1.y;
                g[rr][0] += iv.z * u2.x; g[rr][1] += iv.z * u2.y;
                g[rr][0] += iv.w * u3.x; g[rr][1] += iv.w * u3.y;
            }
        }
    }
    // partials -> LDS (stride-2 writes, conflict-free)
    #pragma unroll
    for (int rr = 0; rr < 8; ++rr)
        *(float2*)&pbuf[((sl << 3) + rr) * 260 + (p2 << 1)] = make_float2(g[rr][0], g[rr][1]);
    __syncthreads();
    // owners: row = t>>6, cols c4 (canonical b128 reads)
    {
        const int orr = t >> 6, c4 = (t & 63) << 2;
        const float4 v0 = *(const float4*)&pbuf[(0 * 8 + orr) * 260 + c4];
        const float4 v1 = *(const float4*)&pbuf[(1 * 8 + orr) * 260 + c4];
        const float4 v2 = *(const float4*)&pbuf[(2 * 8 + orr) * 260 + c4];
        const float4 v3 = *(const float4*)&pbuf[(3 * 8 + orr) * 260 + c4];
        float4 o;
        o.x = (v0.x + v1.x) + (v2.x + v3.x);
        o.y = (v0.y + v1.y) + (v2.y + v3.y);
        o.z = (v0.z + v1.z) + (v2.z + v3.z);
        o.w = (v0.w + v1.w) + (v2.w + v3.w);
        *(float4*)&G[(size_t)(row0 + orr) * KA + c4] = o;
    }
}

// ---------- out = R @ Ut : 512 blocks x 512 thr, 8-row tiles ----------
// thread t -> cols {2t,2t+1}; R tile broadcast from LDS, Ut streamed once/block
__global__ __launch_bounds__(512) void k_out2(const float* __restrict__ Rws,
                                              const float* __restrict__ Ut,
                                              float* __restrict__ out) {
    __shared__ float rt[8 * 256];  // 8 KB
    const int t = threadIdx.x;
    const int row0 = blockIdx.x * 8;
    {
        const int r = t >> 6, cc = (t & 63) << 2;
        *(float4*)&rt[r * 256 + cc] = *(const float4*)&Rws[(size_t)(row0 + r) * KA + cc];
    }
    __syncthreads();
    const int c2 = t << 1;
    float a[8][2];
    #pragma unroll
    for (int r = 0; r < 8; ++r) { a[r][0] = 0.f; a[r][1] = 0.f; }
    #pragma unroll 2
    for (int k = 0; k < 256; k += 4) {
        const float2 u0 = *(const float2*)&Ut[(size_t)(k + 0) * PIX + c2];
        const float2 u1 = *(const float2*)&Ut[(size_t)(k + 1) * PIX + c2];
        const float2 u2 = *(const float2*)&Ut[(size_t)(k + 2) * PIX + c2];
        const float2 u3 = *(const float2*)&Ut[(size_t)(k + 3) * PIX + c2];
        #pragma unroll
        for (int rr = 0; rr < 8; ++rr) {
            const float4 rv = *(const float4*)&rt[rr * 256 + k];  // broadcast
            a[rr][0] += rv.x * u0.x; a[rr][1] += rv.x * u0.y;
            a[rr][0] += rv.y * u1.x; a[rr][1] += rv.y * u1.y;
            a[rr][0] += rv.z * u2.x; a[rr][1] += rv.z * u2.y;
            a[rr][0] += rv.w * u3.x; a[rr][1] += rv.w * u3.y;
        }
    }
    #pragma unroll
    for (int rr = 0; rr < 8; ++rr)
        *(float2*)&out[(size_t)(row0 + rr) * PIX + c2] = make_float2(a[rr][0], a[rr][1]);
}

// ---------- persistent ISTA: S in registers, conflict-free LDS exchange ----------
// dot phase : p2 = t&127 -> cols {2p2, 2p2+1}; sl = t>>7 -> j in [32*sl, 32*sl+32)
// owner     : b_o = t>>6 (row), c4 = (t&63)*4 (4 cols)
__global__ __launch_bounds__(NTHR, 1) void k_ista(const float* __restrict__ S,
                                                  const float* __restrict__ G,
                                                  float* __restrict__ Rws,
                                                  float* partials, int* flags) {
    __shared__ float buf[8 * 4 * 260];   // 33.3 KB: [sl][4 rows][260]
    __shared__ float Rsh[ROWS * KA];     // 16 KB, [b][j]
    __shared__ float red[40];

    const int t = threadIdx.x;
    const int p2 = t & 127, sl = t >> 7, j0 = sl << 5;
    const int b_o = t >> 6;              // == wave id
    const int c4 = (t & 63) << 2;
    const int blk = blockIdx.x, row0 = blk * ROWS;

    // ---- S slice into registers (iteration-invariant) ----
    float2 sreg[32];
    #pragma unroll
    for (int j = 0; j < 32; ++j)
        sreg[j] = *(const float2*)&S[(size_t)(j0 + j) * KA + (p2 << 1)];

    // ---- G for owned outputs ----
    float Gr[4];
    {
        float4 g = *(const float4*)&G[(size_t)(row0 + b_o) * KA + c4];
        Gr[0] = g.x; Gr[1] = g.y; Gr[2] = g.z; Gr[3] = g.w;
    }

    // ---- R = 0 ----
    float Rold[4] = {0.f, 0.f, 0.f, 0.f}, snap[4] = {0.f, 0.f, 0.f, 0.f};
    *(float4*)&Rsh[t << 2] = make_float4(0.f, 0.f, 0.f, 0.f);
    if (t == 0) red[36] = 0.f;
    __syncthreads();

    bool fired = false;

    for (int iter = 0; iter < MAX_ITERS; ++iter) {
        // run-ahead: wave 0 confirms all blocks posted iter-2, sums their partials
        float gsn = 0.f, gsd = 0.f;
        const bool chk = (iter >= 2) && (t < 64);
        if (chk) {
            const int want = iter - 1;  // flag >= iter-1 <=> posted iter-2
            #pragma unroll
            for (int q = 0; q < 4; ++q)
                while (AT_LOAD(&flags[t + (q << 6)]) < want) __builtin_amdgcn_s_sleep(1);
            asm volatile("" ::: "memory");
            const float* ps = partials + (size_t)((iter - 2) & 3) * (2 * NBLK);
            #pragma unroll
            for (int q = 0; q < 4; ++q) {
                gsn += AT_LOAD(&ps[(t + (q << 6)) * 2 + 0]);
                gsd += AT_LOAD(&ps[(t + (q << 6)) * 2 + 1]);
            }
        }

        float num = 0.f, den = 0.f;
        float Nnew[4];

        // ---- 4 chunks of 4 rows: register-S dot + LDS cross-slice reduce ----
        for (int cc = 0; cc < 4; ++cc) {
            float a00 = 0.f, a01 = 0.f, a10 = 0.f, a11 = 0.f;
            float a20 = 0.f, a21 = 0.f, a30 = 0.f, a31 = 0.f;
            const float* Rp = &Rsh[(cc << 2) * KA + j0];
            #pragma unroll
            for (int q = 0; q < 8; ++q) {
                const float4 r0 = *(const float4*)&Rp[0 * KA + (q << 2)];  // broadcast
                const float4 r1 = *(const float4*)&Rp[1 * KA + (q << 2)];
                const float4 r2 = *(const float4*)&Rp[2 * KA + (q << 2)];
                const float4 r3 = *(const float4*)&Rp[3 * KA + (q << 2)];
                #define ISTA_STEP(JJ, X0, X1, X2, X3)                         \
                    { const float2 sv = sreg[(q << 2) + JJ];                  \
                      a00 += (X0) * sv.x; a01 += (X0) * sv.y;                 \
                      a10 += (X1) * sv.x; a11 += (X1) * sv.y;                 \
                      a20 += (X2) * sv.x; a21 += (X2) * sv.y;                 \
                      a30 += (X3) * sv.x; a31 += (X3) * sv.y; }
                ISTA_STEP(0, r0.x, r1.x, r2.x, r3.x)
                ISTA_STEP(1, r0.y, r1.y, r2.y, r3.y)
                ISTA_STEP(2, r0.z, r1.z, r2.z, r3.z)
                ISTA_STEP(3, r0.w, r1.w, r2.w, r3.w)
                #undef ISTA_STEP
            }
            __syncthreads();  // A: prior reduce-reads of buf complete
            {   // stride-2 b64 writes: conflict-free
                float* pw = &buf[(sl << 2) * 260 + (p2 << 1)];
                *(float2*)&pw[0 * 260] = make_float2(a00, a01);
                *(float2*)&pw[1 * 260] = make_float2(a10, a11);
                *(float2*)&pw[2 * 260] = make_float2(a20, a21);
                *(float2*)&pw[3 * 260] = make_float2(a30, a31);
            }
            __syncthreads();  // B: partials visible
            if ((b_o >> 2) == cc) {
                const int rr = b_o & 3;
                // canonical b128 reads (16B lane stride), same slice sum order as R4
                const float4 v0 = *(const float4*)&buf[(0 * 4 + rr) * 260 + c4];
                const float4 v1 = *(const float4*)&buf[(1 * 4 + rr) * 260 + c4];
                const float4 v2 = *(const float4*)&buf[(2 * 4 + rr) * 260 + c4];
                const float4 v3 = *(const float4*)&buf[(3 * 4 + rr) * 260 + c4];
                const float4 v4 = *(const float4*)&buf[(4 * 4 + rr) * 260 + c4];
                const float4 v5 = *(const float4*)&buf[(5 * 4 + rr) * 260 + c4];
                const float4 v6 = *(const float4*)&buf[(6 * 4 + rr) * 260 + c4];
                const float4 v7 = *(const float4*)&buf[(7 * 4 + rr) * 260 + c4];
                float av[4];
                av[0] = ((v0.x + v1.x) + (v2.x + v3.x)) + ((v4.x + v5.x) + (v6.x + v7.x));
                av[1] = ((v0.y + v1.y) + (v2.y + v3.y)) + ((v4.y + v5.y) + (v6.y + v7.y));
                av[2] = ((v0.z + v1.z) + (v2.z + v3.z)) + ((v4.z + v5.z) + (v6.z + v7.z));
                av[3] = ((v0.w + v1.w) + (v2.w + v3.w)) + ((v4.w + v5.w) + (v6.w + v7.w));
                #pragma unroll
                for (int i = 0; i < 4; ++i) {
                    const float v = Rold[i] + LR2 * (Gr[i] - av[i]);
                    const float n = fmaxf(v - LMDA_C, 0.f) - fmaxf(-v - LMDA_C, 0.f);
                    const float d = n - Rold[i];
                    num += d * d; den += Rold[i] * Rold[i];
                    Nnew[i] = n;
                }
                *(float4*)&Rsh[b_o * KA + c4] = make_float4(Nnew[0], Nnew[1], Nnew[2], Nnew[3]);
            }
        }

        // ---- block reduce num/den ----
        #pragma unroll
        for (int off = 32; off > 0; off >>= 1) {
            num += __shfl_down(num, off, 64);
            den += __shfl_down(den, off, 64);
        }
        if ((t & 63) == 0) { red[(t >> 6) * 2] = num; red[(t >> 6) * 2 + 1] = den; }
        __syncthreads();  // C
        if (t == 0) {
            float n = 0.f, d = 0.f;
            #pragma unroll
            for (int i = 0; i < 16; ++i) { n += red[2 * i]; d += red[2 * i + 1]; }
            float* pd = partials + (size_t)(iter & 3) * (2 * NBLK) + blk * 2;
            AT_STORE(&pd[0], n);   // fire-and-forget; flag bump after sync D
            AT_STORE(&pd[1], d);
        }
        if (chk) {  // global decision for iter-2, identical order in every block
            float n = gsn, d = gsd;
            #pragma unroll
            for (int off = 32; off > 0; off >>= 1) {
                n += __shfl_down(n, off, 64);
                d += __shfl_down(d, off, 64);
            }
            if (t == 0) red[36] = (n < TOL2 * d) ? 1.f : 0.f;
        }
        __syncthreads();  // D
        if (t == 0) {
            __builtin_amdgcn_s_waitcnt(0);  // stores drained during decision phase
            __hip_atomic_fetch_add(&flags[blk], 1, __ATOMIC_RELAXED, __HIP_MEMORY_SCOPE_AGENT);
        }
        if (red[36] != 0.f) { fired = true; break; }
        #pragma unroll
        for (int i = 0; i < 4; ++i) { snap[i] = Rold[i]; Rold[i] = Nnew[i]; }
    }

    // ---- store converged iterate (reference returns R_{iter-1} when fired) ----
    {
        float4 v;
        v.x = fired ? snap[0] : Rold[0];
        v.y = fired ? snap[1] : Rold[1];
        v.z = fired ? snap[2] : Rold[2];
        v.w = fired ? snap[3] : Rold[3];
        *(float4*)&Rws[(size_t)(row0 + b_o) * KA + c4] = v;
    }
}

extern "C" void kernel_launch(void* const* d_in, const int* in_sizes, int n_in,
                              void* d_out, int out_size, void* d_ws, size_t ws_size,
                              hipStream_t stream) {
    const float* img = (const float*)d_in[0];  // [4096, 1024]
    const float* U   = (const float*)d_in[1];  // [1024, 256]
    float* out = (float*)d_out;                // [4096, 1024]
    float* ws  = (float*)d_ws;

    float* Ut       = ws;                       // 262144
    float* S        = ws + 262144;              // 65536
    float* G        = ws + 327680;              // 1048576
    float* Rws      = ws + 1376256;             // 1048576
    float* partials = ws + 2424832;             // 4*2*256 = 2048
    int*   flags    = (int*)(ws + 2426880);     // 256

    k_transpose<<<64, 256, 0, stream>>>(U, Ut, flags);
    k_gram<<<256, 256, 0, stream>>>(U, Ut, S);
    k_gemmG2<<<512, 512, 0, stream>>>(img, U, G);

    void* args[] = {(void*)&S, (void*)&G, (void*)&Rws, (void*)&partials, (void*)&flags};
    hipLaunchCooperativeKernel((void*)k_ista, dim3(NBLK), dim3(NTHR), args, 0, stream);

    k_out2<<<512, 512, 0, stream>>>(Rws, Ut, out);
}

// Round 6
// 311.935 us; speedup vs baseline: 2.3255x; 1.5613x over previous
//
#include <hip/hip_runtime.h>

using short8 = __attribute__((ext_vector_type(8))) short;
using f32x4  = __attribute__((ext_vector_type(4))) float;

static constexpr int KA        = 256;    // dictionary atoms
static constexpr int PIX       = 1024;   // M*M
static constexpr int NBLK      = 256;    // cooperative blocks (1/CU)
static constexpr int NTHR      = 1024;   // 16 waves
static constexpr int ROWS      = 16;     // batch rows per block
static constexpr int MAX_ITERS = 2048;
static constexpr float LR2     = 0.2f;   // 2 * R_LR
static constexpr float LMDA_C  = 0.005f;
static constexpr float TOL2    = 1e-4f;  // TOL^2

#define AT_LOAD(p)     __hip_atomic_load((p), __ATOMIC_RELAXED, __HIP_MEMORY_SCOPE_AGENT)
#define AT_STORE(p, v) __hip_atomic_store((p), (v), __ATOMIC_RELAXED, __HIP_MEMORY_SCOPE_AGENT)

__device__ __forceinline__ unsigned short f2bf(float x) {
    unsigned u = __builtin_bit_cast(unsigned, x);
    u = (u + 0x7fffu + ((u >> 16) & 1u)) >> 16;   // RNE
    return (unsigned short)u;
}
__device__ __forceinline__ float bf2f(unsigned short h) {
    unsigned u = ((unsigned)h) << 16;
    return __builtin_bit_cast(float, u);
}

// ---------- prep: blocks 0..63 transpose U -> Ut (+flag zero); 64..319 Gram rows ----------
__global__ __launch_bounds__(256) void k_prep(const float* __restrict__ U,
                                              float* __restrict__ Ut,
                                              float* __restrict__ S,
                                              int* __restrict__ flags) {
    __shared__ float tile[64 * 65];
    __shared__ float col[PIX];
    const int t = threadIdx.x;
    const int b = blockIdx.x;
    if (b < 64) {
        if (b == 0) flags[t] = 0;
        const int bx = b & 3, by = b >> 2;
        const int lane = t & 63, w = t >> 6;
        const int m0 = by * 64, k0 = bx * 64;
        #pragma unroll
        for (int i = 0; i < 16; ++i) {
            const int ml = w * 16 + i;
            tile[lane * 65 + ml] = U[(size_t)(m0 + ml) * KA + k0 + lane];
        }
        __syncthreads();
        #pragma unroll
        for (int i = 0; i < 16; ++i) {
            const int kl = w * 16 + i;
            Ut[(size_t)(k0 + kl) * PIX + m0 + lane] = tile[kl * 65 + lane];
        }
    } else {
        const int i = b - 64;   // gram row i
        #pragma unroll
        for (int q = 0; q < 4; ++q)
            col[t + 256 * q] = U[(size_t)(t + 256 * q) * KA + i];
        __syncthreads();
        float acc = 0.f;
        for (int p = 0; p < PIX; p += 4) {
            float4 cv = *(const float4*)&col[p];
            acc += cv.x * U[(size_t)(p + 0) * KA + t];
            acc += cv.y * U[(size_t)(p + 1) * KA + t];
            acc += cv.z * U[(size_t)(p + 2) * KA + t];
            acc += cv.w * U[(size_t)(p + 3) * KA + t];
        }
        S[(size_t)i * KA + t] = acc;
    }
}

// ---------- fused persistent ISTA: G prologue + MFMA loop + out epilogue ----------
// wave w = t>>6 owns col-tile [16w,16w+16); lane: l15=t&15 (col n / A-row m), quad=(t>>4)&3
// C/D layout: row = quad*4 + i, col = 16w + l15  (bijective over 16x256)
__global__ __launch_bounds__(NTHR, 1) void k_ista(const float* __restrict__ img,
                                                  const float* __restrict__ U,
                                                  const float* __restrict__ S,
                                                  const float* __restrict__ Ut,
                                                  float* __restrict__ Gws,
                                                  float* __restrict__ out,
                                                  float* partials, int* flags) {
    __shared__ float X[16 * 260];             // 16.6 KB: img stage / G-exchange / final R fp32
    __shared__ unsigned short Rhi[16 * 260];  // 8.3 KB  bf16 hi, row stride 260
    __shared__ unsigned short Rlo[16 * 260];  // 8.3 KB  bf16 lo
    __shared__ float red[40];

    const int t    = threadIdx.x;
    const int lane = t & 63;
    const int w    = t >> 6;
    const int l15  = t & 15;
    const int quad = (t >> 4) & 3;
    const int colc = (w << 4) + l15;          // owned column
    const int blk  = blockIdx.x, row0 = blk * ROWS;

    // ================= prologue: G = img @ U (fp32) =================
    const int p2 = t & 127, sl = t >> 7;      // dot-phase mapping
    float g[16][2];
    #pragma unroll
    for (int r = 0; r < 16; ++r) { g[r][0] = 0.f; g[r][1] = 0.f; }

    for (int q = 0; q < 4; ++q) {             // quarter-K phases
        __syncthreads();
        {   // stage img[16 rows][256 k] into X (stride 260)
            const int r = t >> 6, c4s = (t & 63) << 2;
            *(float4*)&X[r * 260 + c4s] =
                *(const float4*)&img[(size_t)(row0 + r) * PIX + (q << 8) + c4s];
        }
        __syncthreads();
        const float* Up = U + (size_t)((q << 8) + (sl << 5)) * KA + (p2 << 1);
        #pragma unroll 2
        for (int jq = 0; jq < 8; ++jq) {
            const float2 u0 = *(const float2*)&Up[(size_t)((jq << 2) + 0) * KA];
            const float2 u1 = *(const float2*)&Up[(size_t)((jq << 2) + 1) * KA];
            const float2 u2 = *(const float2*)&Up[(size_t)((jq << 2) + 2) * KA];
            const float2 u3 = *(const float2*)&Up[(size_t)((jq << 2) + 3) * KA];
            #pragma unroll
            for (int r = 0; r < 16; ++r) {
                const float4 iv = *(const float4*)&X[r * 260 + (sl << 5) + (jq << 2)];
                g[r][0] += iv.x * u0.x; g[r][1] += iv.x * u0.y;
                g[r][0] += iv.y * u1.x; g[r][1] += iv.y * u1.y;
                g[r][0] += iv.z * u2.x; g[r][1] += iv.z * u2.y;
                g[r][0] += iv.w * u3.x; g[r][1] += iv.w * u3.y;
            }
        }
    }
    // cross-slice exchange, 8 chunks of 2 rows; owners write G to global Gws
    #pragma unroll
    for (int cc = 0; cc < 8; ++cc) {
        __syncthreads();
        *(float2*)&X[(sl * 2 + 0) * 260 + (p2 << 1)] = make_float2(g[2 * cc][0], g[2 * cc][1]);
        *(float2*)&X[(sl * 2 + 1) * 260 + (p2 << 1)] = make_float2(g[2 * cc + 1][0], g[2 * cc + 1][1]);
        __syncthreads();
        if ((w >> 1) == cc) {
            const int rr = w & 1, c4o = lane << 2;
            const float4 v0 = *(const float4*)&X[(0 * 2 + rr) * 260 + c4o];
            const float4 v1 = *(const float4*)&X[(1 * 2 + rr) * 260 + c4o];
            const float4 v2 = *(const float4*)&X[(2 * 2 + rr) * 260 + c4o];
            const float4 v3 = *(const float4*)&X[(3 * 2 + rr) * 260 + c4o];
            const float4 v4 = *(const float4*)&X[(4 * 2 + rr) * 260 + c4o];
            const float4 v5 = *(const float4*)&X[(5 * 2 + rr) * 260 + c4o];
            const float4 v6 = *(const float4*)&X[(6 * 2 + rr) * 260 + c4o];
            const float4 v7 = *(const float4*)&X[(7 * 2 + rr) * 260 + c4o];
            float4 o;
            o.x = ((v0.x + v1.x) + (v2.x + v3.x)) + ((v4.x + v5.x) + (v6.x + v7.x));
            o.y = ((v0.y + v1.y) + (v2.y + v3.y)) + ((v4.y + v5.y) + (v6.y + v7.y));
            o.z = ((v0.z + v1.z) + (v2.z + v3.z)) + ((v4.z + v5.z) + (v6.z + v7.z));
            o.w = ((v0.w + v1.w) + (v2.w + v3.w)) + ((v4.w + v5.w) + (v6.w + v7.w));
            *(float4*)&Gws[(size_t)(row0 + w) * KA + c4o] = o;
        }
    }
    __syncthreads();   // drains vmcnt: Gws visible via L2

    // ---- G in C-layout registers ----
    float Gr[4];
    #pragma unroll
    for (int i = 0; i < 4; ++i)
        Gr[i] = Gws[(size_t)(row0 + (quad << 2) + i) * KA + colc];

    // ---- B-fragments: split-bf16 S, resident in registers for the whole run ----
    short8 Bhi[8], Blo[8];
    #pragma unroll
    for (int s = 0; s < 8; ++s) {
        #pragma unroll
        for (int j = 0; j < 8; ++j) {
            const float x = S[(size_t)((s << 5) + (quad << 3) + j) * KA + colc];
            const unsigned short hb = f2bf(x);
            Bhi[s][j] = (short)hb;
            Blo[s][j] = (short)f2bf(x - bf2f(hb));
        }
    }

    // ---- R = 0 ----
    float Rold[4] = {0.f, 0.f, 0.f, 0.f}, snap[4] = {0.f, 0.f, 0.f, 0.f};
    for (int idx = t; idx < 16 * 260; idx += NTHR) { Rhi[idx] = 0; Rlo[idx] = 0; }
    if (t == 0) red[36] = 0.f;
    __syncthreads();

    bool fired = false;

    // ================= ISTA loop =================
    for (int iter = 0; iter < MAX_ITERS; ++iter) {
        // run-ahead: wave 0 confirms all blocks posted iter-2, pre-loads partials
        float gsn = 0.f, gsd = 0.f;
        const bool chk = (iter >= 2) && (t < 64);
        if (chk) {
            const int want = iter - 1;
            #pragma unroll
            for (int qq = 0; qq < 4; ++qq)
                while (AT_LOAD(&flags[t + (qq << 6)]) < want) __builtin_amdgcn_s_sleep(1);
            asm volatile("" ::: "memory");
            const float* ps = partials + (size_t)((iter - 2) & 3) * (2 * NBLK);
            #pragma unroll
            for (int qq = 0; qq < 4; ++qq) {
                gsn += AT_LOAD(&ps[(t + (qq << 6)) * 2 + 0]);
                gsd += AT_LOAD(&ps[(t + (qq << 6)) * 2 + 1]);
            }
        }

        // ---- a = R*S via split-bf16 MFMA (3 products, drop lo*lo) ----
        f32x4 acc = {0.f, 0.f, 0.f, 0.f};
        const int arow = l15 * 260;
        #pragma unroll
        for (int s = 0; s < 8; ++s) {
            const int ab = arow + (s << 5) + (quad << 3);
            union { uint2 qv[2]; short8 v; } ah, al;
            ah.qv[0] = *(const uint2*)&Rhi[ab];
            ah.qv[1] = *(const uint2*)&Rhi[ab + 4];
            al.qv[0] = *(const uint2*)&Rlo[ab];
            al.qv[1] = *(const uint2*)&Rlo[ab + 4];
            acc = __builtin_amdgcn_mfma_f32_16x16x32_bf16(ah.v, Bhi[s], acc, 0, 0, 0);
            acc = __builtin_amdgcn_mfma_f32_16x16x32_bf16(ah.v, Blo[s], acc, 0, 0, 0);
            acc = __builtin_amdgcn_mfma_f32_16x16x32_bf16(al.v, Bhi[s], acc, 0, 0, 0);
        }

        // ---- shrink + num/den (C-layout ownership) ----
        float num = 0.f, den = 0.f, Nnew[4];
        #pragma unroll
        for (int i = 0; i < 4; ++i) {
            const float v = Rold[i] + LR2 * (Gr[i] - acc[i]);
            const float n = fmaxf(v - LMDA_C, 0.f) - fmaxf(-v - LMDA_C, 0.f);
            const float d = n - Rold[i];
            num += d * d; den += Rold[i] * Rold[i];
            Nnew[i] = n;
        }
        __syncthreads();  // E1: all A-frag reads complete before R overwrite
        #pragma unroll
        for (int i = 0; i < 4; ++i) {
            const int idx = ((quad << 2) + i) * 260 + colc;
            const unsigned short hb = f2bf(Nnew[i]);
            Rhi[idx] = hb;
            Rlo[idx] = f2bf(Nnew[i] - bf2f(hb));
        }

        // ---- block reduce ----
        #pragma unroll
        for (int off = 32; off > 0; off >>= 1) {
            num += __shfl_down(num, off, 64);
            den += __shfl_down(den, off, 64);
        }
        if (lane == 0) { red[w * 2] = num; red[w * 2 + 1] = den; }
        __syncthreads();  // C
        if (t == 0) {
            float n = 0.f, d = 0.f;
            #pragma unroll
            for (int i = 0; i < 16; ++i) { n += red[2 * i]; d += red[2 * i + 1]; }
            float* pd = partials + (size_t)(iter & 3) * (2 * NBLK) + blk * 2;
            AT_STORE(&pd[0], n);
            AT_STORE(&pd[1], d);
        }
        if (chk) {   // global decision for iter-2, identical order everywhere
            float n = gsn, d = gsd;
            #pragma unroll
            for (int off = 32; off > 0; off >>= 1) {
                n += __shfl_down(n, off, 64);
                d += __shfl_down(d, off, 64);
            }
            if (t == 0) red[36] = (n < TOL2 * d) ? 1.f : 0.f;
        }
        __syncthreads();  // D
        if (t == 0) {
            __builtin_amdgcn_s_waitcnt(0);  // partial stores at coherence point
            __hip_atomic_fetch_add(&flags[blk], 1, __ATOMIC_RELAXED, __HIP_MEMORY_SCOPE_AGENT);
        }
        if (red[36] != 0.f) { fired = true; break; }  // output R_{iter-1}
        #pragma unroll
        for (int i = 0; i < 4; ++i) { snap[i] = Rold[i]; Rold[i] = Nnew[i]; }
    }

    // ================= epilogue: out = R @ Ut =================
    __syncthreads();
    #pragma unroll
    for (int i = 0; i < 4; ++i)
        X[((quad << 2) + i) * 260 + colc] = fired ? snap[i] : Rold[i];
    __syncthreads();

    float a[16];
    #pragma unroll
    for (int r = 0; r < 16; ++r) a[r] = 0.f;
    const int ct = t;   // output column
    #pragma unroll 4
    for (int kq = 0; kq < 64; ++kq) {
        const float u0 = Ut[(size_t)((kq << 2) + 0) * PIX + ct];
        const float u1 = Ut[(size_t)((kq << 2) + 1) * PIX + ct];
        const float u2 = Ut[(size_t)((kq << 2) + 2) * PIX + ct];
        const float u3 = Ut[(size_t)((kq << 2) + 3) * PIX + ct];
        #pragma unroll
        for (int r = 0; r < 16; ++r) {
            const float4 rv = *(const float4*)&X[r * 260 + (kq << 2)];  // broadcast
            a[r] += rv.x * u0 + rv.y * u1 + rv.z * u2 + rv.w * u3;
        }
    }
    #pragma unroll
    for (int r = 0; r < 16; ++r)
        out[(size_t)(row0 + r) * PIX + ct] = a[r];
}

extern "C" void kernel_launch(void* const* d_in, const int* in_sizes, int n_in,
                              void* d_out, int out_size, void* d_ws, size_t ws_size,
                              hipStream_t stream) {
    const float* img = (const float*)d_in[0];  // [4096, 1024]
    const float* U   = (const float*)d_in[1];  // [1024, 256]
    float* out = (float*)d_out;                // [4096, 1024]
    float* ws  = (float*)d_ws;

    float* Ut       = ws;                       // 262144 floats
    float* S        = ws + 262144;              // 65536
    float* Gws      = ws + 327680;              // 1048576
    float* partials = ws + 1376256;             // 4*2*256 = 2048
    int*   flags    = (int*)(ws + 1378304);     // 256 ints

    k_prep<<<320, 256, 0, stream>>>(U, Ut, S, flags);

    void* args[] = {(void*)&img, (void*)&U, (void*)&S, (void*)&Ut,
                    (void*)&Gws, (void*)&out, (void*)&partials, (void*)&flags};
    hipLaunchCooperativeKernel((void*)k_ista, dim3(NBLK), dim3(NTHR), args, 0, stream);
}

// Round 7
// 287.759 us; speedup vs baseline: 2.5209x; 1.0840x over previous
//
#include <hip/hip_runtime.h>

using short8 = __attribute__((ext_vector_type(8))) short;
using f32x4  = __attribute__((ext_vector_type(4))) float;

static constexpr int KA        = 256;    // dictionary atoms
static constexpr int PIX       = 1024;   // M*M
static constexpr int NBLK      = 256;    // cooperative blocks (1/CU)
static constexpr int NTHR      = 1024;   // 16 waves
static constexpr int ROWS      = 16;     // batch rows per block
static constexpr int MAX_ITERS = 2048;
static constexpr float LR2     = 0.2f;   // 2 * R_LR
static constexpr float LMDA_C  = 0.005f;
static constexpr float TOL2    = 1e-4f;  // TOL^2

#define AT_LOAD(p)     __hip_atomic_load((p), __ATOMIC_RELAXED, __HIP_MEMORY_SCOPE_AGENT)
#define AT_STORE(p, v) __hip_atomic_store((p), (v), __ATOMIC_RELAXED, __HIP_MEMORY_SCOPE_AGENT)

__device__ __forceinline__ unsigned short f2bf(float x) {
    unsigned u = __builtin_bit_cast(unsigned, x);
    u = (u + 0x7fffu + ((u >> 16) & 1u)) >> 16;   // RNE
    return (unsigned short)u;
}
__device__ __forceinline__ float bf2f(unsigned short h) {
    unsigned u = ((unsigned)h) << 16;
    return __builtin_bit_cast(float, u);
}

// ---------- prep: blocks 0..63 transpose U -> Ut (+flag zero); 64..319 Gram rows ----------
__global__ __launch_bounds__(256) void k_prep(const float* __restrict__ U,
                                              float* __restrict__ Ut,
                                              float* __restrict__ S,
                                              int* __restrict__ flags) {
    __shared__ float tile[64 * 65];
    __shared__ float col[PIX];
    const int t = threadIdx.x;
    const int b = blockIdx.x;
    if (b < 64) {
        if (b == 0) flags[t] = 0;
        const int bx = b & 3, by = b >> 2;
        const int lane = t & 63, w = t >> 6;
        const int m0 = by * 64, k0 = bx * 64;
        #pragma unroll
        for (int i = 0; i < 16; ++i) {
            const int ml = w * 16 + i;
            tile[lane * 65 + ml] = U[(size_t)(m0 + ml) * KA + k0 + lane];
        }
        __syncthreads();
        #pragma unroll
        for (int i = 0; i < 16; ++i) {
            const int kl = w * 16 + i;
            Ut[(size_t)(k0 + kl) * PIX + m0 + lane] = tile[kl * 65 + lane];
        }
    } else {
        const int i = b - 64;   // gram row i
        #pragma unroll
        for (int q = 0; q < 4; ++q)
            col[t + 256 * q] = U[(size_t)(t + 256 * q) * KA + i];
        __syncthreads();
        float acc = 0.f;
        for (int p = 0; p < PIX; p += 4) {
            float4 cv = *(const float4*)&col[p];
            acc += cv.x * U[(size_t)(p + 0) * KA + t];
            acc += cv.y * U[(size_t)(p + 1) * KA + t];
            acc += cv.z * U[(size_t)(p + 2) * KA + t];
            acc += cv.w * U[(size_t)(p + 3) * KA + t];
        }
        S[(size_t)i * KA + t] = acc;
    }
}

// ---------- fused persistent ISTA: G prologue + MFMA loop + out epilogue ----------
// wave w = t>>6 owns col-tile [16w,16w+16); lane: l15=t&15 (col n / A-row m), quad=(t>>4)&3
// C/D layout: row = quad*4 + i, col = 16w + l15
__global__ __launch_bounds__(NTHR, 1) void k_ista(const float* __restrict__ img,
                                                  const float* __restrict__ U,
                                                  const float* __restrict__ S,
                                                  const float* __restrict__ Ut,
                                                  float* __restrict__ Gws,
                                                  float* __restrict__ out,
                                                  float* partials, int* flags) {
    __shared__ float X[16 * 260];                // 16.6 KB: img stage / G-exchange / final R
    __shared__ unsigned short Rhi[2][16 * 260];  // 2 x 8.3 KB, parity double-buffer
    __shared__ unsigned short Rlo[2][16 * 260];  // 2 x 8.3 KB
    __shared__ float red[44];

    const int t    = threadIdx.x;
    const int lane = t & 63;
    const int w    = t >> 6;
    const int l15  = t & 15;
    const int quad = (t >> 4) & 3;
    const int colc = (w << 4) + l15;          // owned column
    const int blk  = blockIdx.x, row0 = blk * ROWS;

    // ================= prologue: G = img @ U (fp32) =================
    const int p2 = t & 127, sl = t >> 7;
    float g[16][2];
    #pragma unroll
    for (int r = 0; r < 16; ++r) { g[r][0] = 0.f; g[r][1] = 0.f; }

    for (int q = 0; q < 4; ++q) {
        __syncthreads();
        {   // stage img[16 rows][256 k] into X (stride 260)
            const int r = t >> 6, c4s = (t & 63) << 2;
            *(float4*)&X[r * 260 + c4s] =
                *(const float4*)&img[(size_t)(row0 + r) * PIX + (q << 8) + c4s];
        }
        __syncthreads();
        const float* Up = U + (size_t)((q << 8) + (sl << 5)) * KA + (p2 << 1);
        #pragma unroll 2
        for (int jq = 0; jq < 8; ++jq) {
            const float2 u0 = *(const float2*)&Up[(size_t)((jq << 2) + 0) * KA];
            const float2 u1 = *(const float2*)&Up[(size_t)((jq << 2) + 1) * KA];
            const float2 u2 = *(const float2*)&Up[(size_t)((jq << 2) + 2) * KA];
            const float2 u3 = *(const float2*)&Up[(size_t)((jq << 2) + 3) * KA];
            #pragma unroll
            for (int r = 0; r < 16; ++r) {
                const float4 iv = *(const float4*)&X[r * 260 + (sl << 5) + (jq << 2)];
                g[r][0] += iv.x * u0.x; g[r][1] += iv.x * u0.y;
                g[r][0] += iv.y * u1.x; g[r][1] += iv.y * u1.y;
                g[r][0] += iv.z * u2.x; g[r][1] += iv.z * u2.y;
                g[r][0] += iv.w * u3.x; g[r][1] += iv.w * u3.y;
            }
        }
    }
    #pragma unroll
    for (int cc = 0; cc < 8; ++cc) {
        __syncthreads();
        *(float2*)&X[(sl * 2 + 0) * 260 + (p2 << 1)] = make_float2(g[2 * cc][0], g[2 * cc][1]);
        *(float2*)&X[(sl * 2 + 1) * 260 + (p2 << 1)] = make_float2(g[2 * cc + 1][0], g[2 * cc + 1][1]);
        __syncthreads();
        if ((w >> 1) == cc) {
            const int rr = w & 1, c4o = lane << 2;
            const float4 v0 = *(const float4*)&X[(0 * 2 + rr) * 260 + c4o];
            const float4 v1 = *(const float4*)&X[(1 * 2 + rr) * 260 + c4o];
            const float4 v2 = *(const float4*)&X[(2 * 2 + rr) * 260 + c4o];
            const float4 v3 = *(const float4*)&X[(3 * 2 + rr) * 260 + c4o];
            const float4 v4 = *(const float4*)&X[(4 * 2 + rr) * 260 + c4o];
            const float4 v5 = *(const float4*)&X[(5 * 2 + rr) * 260 + c4o];
            const float4 v6 = *(const float4*)&X[(6 * 2 + rr) * 260 + c4o];
            const float4 v7 = *(const float4*)&X[(7 * 2 + rr) * 260 + c4o];
            float4 o;
            o.x = ((v0.x + v1.x) + (v2.x + v3.x)) + ((v4.x + v5.x) + (v6.x + v7.x));
            o.y = ((v0.y + v1.y) + (v2.y + v3.y)) + ((v4.y + v5.y) + (v6.y + v7.y));
            o.z = ((v0.z + v1.z) + (v2.z + v3.z)) + ((v4.z + v5.z) + (v6.z + v7.z));
            o.w = ((v0.w + v1.w) + (v2.w + v3.w)) + ((v4.w + v5.w) + (v6.w + v7.w));
            *(float4*)&Gws[(size_t)(row0 + w) * KA + c4o] = o;
        }
    }
    __syncthreads();

    // ---- G in C-layout registers ----
    float Gr[4];
    #pragma unroll
    for (int i = 0; i < 4; ++i)
        Gr[i] = Gws[(size_t)(row0 + (quad << 2) + i) * KA + colc];

    // ---- B-fragments: split-bf16 S, register-resident ----
    short8 Bhi[8], Blo[8];
    #pragma unroll
    for (int s = 0; s < 8; ++s) {
        #pragma unroll
        for (int j = 0; j < 8; ++j) {
            const float x = S[(size_t)((s << 5) + (quad << 3) + j) * KA + colc];
            const unsigned short hb = f2bf(x);
            Bhi[s][j] = (short)hb;
            Blo[s][j] = (short)f2bf(x - bf2f(hb));
        }
    }

    // ---- R = 0 (both parities) ----
    float Rold[4] = {0.f, 0.f, 0.f, 0.f};
    float snap[4] = {0.f, 0.f, 0.f, 0.f}, snap2[4] = {0.f, 0.f, 0.f, 0.f};
    for (int idx = t; idx < 16 * 260; idx += NTHR) {
        Rhi[0][idx] = 0; Rhi[1][idx] = 0; Rlo[0][idx] = 0; Rlo[1][idx] = 0;
    }
    if (t == 0) red[40] = 0.f;
    __syncthreads();

    bool fired = false;

    // ================= ISTA loop (lag-3 decision, 2 syncs/iter) =================
    for (int iter = 0; iter < MAX_ITERS; ++iter) {
        const int par = iter & 1;

        // distributed run-ahead: t<256 each polls ONE flag, loads ONE partial pair
        float gsn = 0.f, gsd = 0.f;
        const bool chk = (iter >= 3) && (t < 256);
        if (chk) {
            const int want = iter - 2;   // flag >= iter-2  <=>  partials of iter-3 visible
            while (AT_LOAD(&flags[t]) < want) __builtin_amdgcn_s_sleep(1);
            asm volatile("" ::: "memory");
            const float* ps = partials + (size_t)((iter - 3) & 7) * (2 * NBLK);
            gsn = AT_LOAD(&ps[t * 2 + 0]);
            gsd = AT_LOAD(&ps[t * 2 + 1]);
        }

        // ---- a = R*S via split-bf16 MFMA (read parity par) ----
        f32x4 acc = {0.f, 0.f, 0.f, 0.f};
        const int arow = l15 * 260;
        #pragma unroll
        for (int s = 0; s < 8; ++s) {
            const int ab = arow + (s << 5) + (quad << 3);
            union { uint2 qv[2]; short8 v; } ah, al;
            ah.qv[0] = *(const uint2*)&Rhi[par][ab];
            ah.qv[1] = *(const uint2*)&Rhi[par][ab + 4];
            al.qv[0] = *(const uint2*)&Rlo[par][ab];
            al.qv[1] = *(const uint2*)&Rlo[par][ab + 4];
            acc = __builtin_amdgcn_mfma_f32_16x16x32_bf16(ah.v, Bhi[s], acc, 0, 0, 0);
            acc = __builtin_amdgcn_mfma_f32_16x16x32_bf16(ah.v, Blo[s], acc, 0, 0, 0);
            acc = __builtin_amdgcn_mfma_f32_16x16x32_bf16(al.v, Bhi[s], acc, 0, 0, 0);
        }

        // ---- shrink + num/den; write parity par^1 (no sync needed: DB) ----
        float num = 0.f, den = 0.f, Nnew[4];
        #pragma unroll
        for (int i = 0; i < 4; ++i) {
            const float v = Rold[i] + LR2 * (Gr[i] - acc[i]);
            const float n = fmaxf(v - LMDA_C, 0.f) - fmaxf(-v - LMDA_C, 0.f);
            const float d = n - Rold[i];
            num += d * d; den += Rold[i] * Rold[i];
            Nnew[i] = n;
        }
        #pragma unroll
        for (int i = 0; i < 4; ++i) {
            const int idx = ((quad << 2) + i) * 260 + colc;
            const unsigned short hb = f2bf(Nnew[i]);
            Rhi[par ^ 1][idx] = hb;
            Rlo[par ^ 1][idx] = f2bf(Nnew[i] - bf2f(hb));
        }

        // ---- reduce own num/den; waves 0-3 reduce the global pairs ----
        #pragma unroll
        for (int off = 32; off > 0; off >>= 1) {
            num += __shfl_down(num, off, 64);
            den += __shfl_down(den, off, 64);
        }
        if (lane == 0) { red[w * 2] = num; red[w * 2 + 1] = den; }
        if (chk) {
            #pragma unroll
            for (int off = 32; off > 0; off >>= 1) {
                gsn += __shfl_down(gsn, off, 64);
                gsd += __shfl_down(gsd, off, 64);
            }
            if (lane == 0) { red[32 + w * 2] = gsn; red[33 + w * 2] = gsd; }
        }
        __syncthreads();  // S1: R writes, own pairs, global pairs all visible

        if (t == 0) {
            if (iter >= 1) {
                __builtin_amdgcn_s_waitcnt(0);  // iter-1's partial stores long drained
                __hip_atomic_fetch_add(&flags[blk], 1, __ATOMIC_RELAXED,
                                       __HIP_MEMORY_SCOPE_AGENT);  // flag = iter
            }
            float n = 0.f, d = 0.f;
            #pragma unroll
            for (int i = 0; i < 16; ++i) { n += red[2 * i]; d += red[2 * i + 1]; }
            float* pd = partials + (size_t)(iter & 7) * (2 * NBLK) + blk * 2;
            AT_STORE(&pd[0], n);
            AT_STORE(&pd[1], d);
            if (iter >= 3) {
                const float gn = ((red[32] + red[34]) + (red[36] + red[38]));
                const float gd = ((red[33] + red[35]) + (red[37] + red[39]));
                red[40] = (gn < TOL2 * gd) ? 1.f : 0.f;
            }
        }
        __syncthreads();  // S2: decision visible

        if (red[40] != 0.f) { fired = true; break; }  // ratio_{iter-3} < TOL -> R_{iter-2}
        #pragma unroll
        for (int i = 0; i < 4; ++i) { snap2[i] = snap[i]; snap[i] = Rold[i]; Rold[i] = Nnew[i]; }
    }

    // ================= epilogue: out = R @ Ut =================
    __syncthreads();
    #pragma unroll
    for (int i = 0; i < 4; ++i)
        X[((quad << 2) + i) * 260 + colc] = fired ? snap2[i] : Rold[i];
    __syncthreads();

    float a[16];
    #pragma unroll
    for (int r = 0; r < 16; ++r) a[r] = 0.f;
    const int ct = t;
    #pragma unroll 4
    for (int kq = 0; kq < 64; ++kq) {
        const float u0 = Ut[(size_t)((kq << 2) + 0) * PIX + ct];
        const float u1 = Ut[(size_t)((kq << 2) + 1) * PIX + ct];
        const float u2 = Ut[(size_t)((kq << 2) + 2) * PIX + ct];
        const float u3 = Ut[(size_t)((kq << 2) + 3) * PIX + ct];
        #pragma unroll
        for (int r = 0; r < 16; ++r) {
            const float4 rv = *(const float4*)&X[r * 260 + (kq << 2)];  // broadcast
            a[r] += rv.x * u0 + rv.y * u1 + rv.z * u2 + rv.w * u3;
        }
    }
    #pragma unroll
    for (int r = 0; r < 16; ++r)
        out[(size_t)(row0 + r) * PIX + ct] = a[r];
}

extern "C" void kernel_launch(void* const* d_in, const int* in_sizes, int n_in,
                              void* d_out, int out_size, void* d_ws, size_t ws_size,
                              hipStream_t stream) {
    const float* img = (const float*)d_in[0];  // [4096, 1024]
    const float* U   = (const float*)d_in[1];  // [1024, 256]
    float* out = (float*)d_out;                // [4096, 1024]
    float* ws  = (float*)d_ws;

    float* Ut       = ws;                       // 262144 floats
    float* S        = ws + 262144;              // 65536
    float* Gws      = ws + 327680;              // 1048576
    float* partials = ws + 1376256;             // 8 slots * 2 * NBLK = 4096
    int*   flags    = (int*)(ws + 1380352);     // 256 ints

    k_prep<<<320, 256, 0, stream>>>(U, Ut, S, flags);

    void* args[] = {(void*)&img, (void*)&U, (void*)&S, (void*)&Ut,
                    (void*)&Gws, (void*)&out, (void*)&partials, (void*)&flags};
    hipLaunchCooperativeKernel((void*)k_ista, dim3(NBLK), dim3(NTHR), args, 0, stream);
}

// Round 8
// 283.048 us; speedup vs baseline: 2.5628x; 1.0166x over previous
//
#include <hip/hip_runtime.h>

using short8 = __attribute__((ext_vector_type(8))) short;
using f32x4  = __attribute__((ext_vector_type(4))) float;

static constexpr int KA        = 256;    // dictionary atoms
static constexpr int PIX       = 1024;   // M*M
static constexpr int NBLK      = 256;    // cooperative blocks (1/CU)
static constexpr int NTHR      = 1024;   // 16 waves
static constexpr int ROWS      = 16;     // batch rows per block
static constexpr int MAX_ITERS = 2048;
static constexpr float LR2     = 0.2f;   // 2 * R_LR
static constexpr float LMDA_C  = 0.005f;
static constexpr float TOL2    = 1e-4f;  // TOL^2

#define AT_LOAD(p)     __hip_atomic_load((p), __ATOMIC_RELAXED, __HIP_MEMORY_SCOPE_AGENT)
#define AT_STORE(p, v) __hip_atomic_store((p), (v), __ATOMIC_RELAXED, __HIP_MEMORY_SCOPE_AGENT)

__device__ __forceinline__ unsigned short f2bf(float x) {
    unsigned u = __builtin_bit_cast(unsigned, x);
    u = (u + 0x7fffu + ((u >> 16) & 1u)) >> 16;   // RNE
    return (unsigned short)u;
}
__device__ __forceinline__ float bf2f(unsigned short h) {
    unsigned u = ((unsigned)h) << 16;
    return __builtin_bit_cast(float, u);
}

// ---------- prep ----------
// blocks 0..255   : Gram row i = b (S = U^T U), block 0 also zeroes flags
// blocks 256..271 : UG frag swizzle (G-GEMM B operand, tile w = b-256), hi/lo
// blocks 272..335 : UtB frag swizzle (out-GEMM B operand, tile ot = b-272), hi/lo
__global__ __launch_bounds__(256) void k_prep(const float* __restrict__ U,
                                              float* __restrict__ S,
                                              unsigned short* __restrict__ UGh,
                                              unsigned short* __restrict__ UGl,
                                              unsigned short* __restrict__ UtBh,
                                              unsigned short* __restrict__ UtBl,
                                              int* __restrict__ flags) {
    const int t = threadIdx.x, b = blockIdx.x;
    if (b < 256) {
        if (b == 0) flags[t] = 0;
        __shared__ float col[PIX];
        const int i = b;
        #pragma unroll
        for (int q = 0; q < 4; ++q)
            col[t + 256 * q] = U[(size_t)(t + 256 * q) * KA + i];
        __syncthreads();
        float acc = 0.f;
        for (int p = 0; p < PIX; p += 4) {
            float4 cv = *(const float4*)&col[p];
            acc += cv.x * U[(size_t)(p + 0) * KA + t];
            acc += cv.y * U[(size_t)(p + 1) * KA + t];
            acc += cv.z * U[(size_t)(p + 2) * KA + t];
            acc += cv.w * U[(size_t)(p + 3) * KA + t];
        }
        S[(size_t)i * KA + t] = acc;
    } else if (b < 272) {
        const int w = b - 256;
        #pragma unroll 4
        for (int e = 0; e < 64; ++e) {
            const int idx = e * 256 + t;                 // (s*64+lane)*8+j
            const int s = idx >> 9, lane = (idx >> 3) & 63, j = idx & 7;
            const int k = s * 32 + ((lane >> 4) << 3) + j;
            const int c = (w << 4) + (lane & 15);
            const float x = U[(size_t)k * KA + c];
            const unsigned short hb = f2bf(x);
            UGh[w * 16384 + idx] = hb;
            UGl[w * 16384 + idx] = f2bf(x - bf2f(hb));
        }
    } else {
        const int ot = b - 272;
        #pragma unroll 4
        for (int e = 0; e < 16; ++e) {
            const int idx = e * 256 + t;                 // (s*64+lane)*8+j
            const int s = idx >> 9, lane = (idx >> 3) & 63, j = idx & 7;
            const int k = s * 32 + ((lane >> 4) << 3) + j;
            const int c = (ot << 4) + (lane & 15);
            const float x = U[(size_t)c * KA + k];       // Ut[k][c] = U[c][k]
            const unsigned short hb = f2bf(x);
            UtBh[ot * 4096 + idx] = hb;
            UtBl[ot * 4096 + idx] = f2bf(x - bf2f(hb));
        }
    }
}

#define MFMA_BF16 __builtin_amdgcn_mfma_f32_16x16x32_bf16

// ---------- fused persistent ISTA, single barrier per iteration ----------
// wave w owns col-tile [16w,16w+16); l15 = A-row m / C-col; quad = k-subgroup
// C/D: row = quad*4 + i, col = 16w + l15
__global__ __launch_bounds__(NTHR, 1) void k_ista(const float* __restrict__ img,
                                                  const float* __restrict__ S,
                                                  const unsigned short* __restrict__ UGh,
                                                  const unsigned short* __restrict__ UGl,
                                                  const unsigned short* __restrict__ UtBh,
                                                  const unsigned short* __restrict__ UtBl,
                                                  float* __restrict__ out,
                                                  float* partials, int* flags) {
    __shared__ unsigned short Ihi[4 * 4160];     // img A-frags, 4 chunks x [16][260]
    __shared__ unsigned short Ilo[4 * 4160];
    __shared__ unsigned short Rhi[2][4160];      // R parity DB, [16][260]
    __shared__ unsigned short Rlo[2][4160];
    __shared__ float redL[2][32];                // per-wave num/den pairs (parity DB)
    __shared__ float red32[2][8];                // waves0-3 global-partial sums (parity DB)
    __shared__ float red40[2];                   // decision (parity DB)

    const int t    = threadIdx.x;
    const int lane = t & 63;
    const int w    = t >> 6;
    const int l15  = t & 15;
    const int quad = (t >> 4) & 3;
    const int colc = (w << 4) + l15;
    const int blk  = blockIdx.x, row0 = blk * ROWS;

    // ---- init R=0 (both parities) + decision slots ----
    for (int idx = t; idx < 4160; idx += NTHR) {
        Rhi[0][idx] = 0; Rhi[1][idx] = 0; Rlo[0][idx] = 0; Rlo[1][idx] = 0;
    }
    if (t == 0) { red40[0] = 0.f; red40[1] = 0.f; }

    // ---- stage img as split-bf16 A-frags (chunked stride-260, conflict-free) ----
    {
        const int chunk = t >> 8, kk = t & 255;
        #pragma unroll
        for (int e = 0; e < 16; ++e) {
            const float x = img[(size_t)(row0 + e) * PIX + (chunk << 8) + kk];
            const unsigned short hb = f2bf(x);
            Ihi[chunk * 4160 + e * 260 + kk] = hb;
            Ilo[chunk * 4160 + e * 260 + kk] = f2bf(x - bf2f(hb));
        }
    }
    __syncthreads();

    // ---- prologue: G = img @ U via MFMA, lands directly in C-layout ----
    float Gr[4];
    {
        f32x4 aH = {0.f, 0.f, 0.f, 0.f}, aM = {0.f, 0.f, 0.f, 0.f}, aL = {0.f, 0.f, 0.f, 0.f};
        const unsigned short* ugh = UGh + ((size_t)w << 14) + ((size_t)lane << 3);
        const unsigned short* ugl = UGl + ((size_t)w << 14) + ((size_t)lane << 3);
        #pragma unroll
        for (int s = 0; s < 32; ++s) {
            const int ab = (s >> 3) * 4160 + l15 * 260 + (s & 7) * 32 + (quad << 3);
            union { uint2 q[2]; short8 v; } ah, al;
            ah.q[0] = *(const uint2*)&Ihi[ab]; ah.q[1] = *(const uint2*)&Ihi[ab + 4];
            al.q[0] = *(const uint2*)&Ilo[ab]; al.q[1] = *(const uint2*)&Ilo[ab + 4];
            const short8 bh = *(const short8*)&ugh[(size_t)s << 9];
            const short8 bl = *(const short8*)&ugl[(size_t)s << 9];
            aH = MFMA_BF16(ah.v, bh, aH, 0, 0, 0);
            aM = MFMA_BF16(ah.v, bl, aM, 0, 0, 0);
            aL = MFMA_BF16(al.v, bh, aL, 0, 0, 0);
        }
        #pragma unroll
        for (int i = 0; i < 4; ++i) Gr[i] = (aH[i] + aM[i]) + aL[i];
    }

    // ---- S B-fragments: split-bf16, register-resident ----
    short8 Bhi[8], Blo[8];
    #pragma unroll
    for (int s = 0; s < 8; ++s) {
        #pragma unroll
        for (int j = 0; j < 8; ++j) {
            const float x = S[(size_t)((s << 5) + (quad << 3) + j) * KA + colc];
            const unsigned short hb = f2bf(x);
            Bhi[s][j] = (short)hb;
            Blo[s][j] = (short)f2bf(x - bf2f(hb));
        }
    }

    float Rold[4] = {0.f, 0.f, 0.f, 0.f};
    float sn0[4] = {0.f, 0.f, 0.f, 0.f}, sn1[4] = {0.f, 0.f, 0.f, 0.f};
    float sn2[4] = {0.f, 0.f, 0.f, 0.f}, sn3[4] = {0.f, 0.f, 0.f, 0.f};
    int flagv = 0;
    bool fired = false;
    int fslot = 0;

    // ================= ISTA loop: ONE barrier per iteration =================
    for (int iter = 0; iter < MAX_ITERS; ++iter) {
        __syncthreads();  // B_iter: prev iter's R[par], redL, red32, red40 all visible
        if (red40[(iter + 1) & 1] != 0.f) { fired = true; fslot = iter & 3; break; }

        const int par = iter & 1;

        // ---- housekeeping on wave 15 (t==960): runs in parallel with MFMA waves ----
        if (t == 960) {
            if (iter >= 2) {
                __builtin_amdgcn_s_waitcnt(0);  // drains partial store issued at iter-1
                __hip_atomic_fetch_add(&flags[blk], 1, __ATOMIC_RELAXED,
                                       __HIP_MEMORY_SCOPE_AGENT);  // flag = iter-1
            }
            if (iter >= 1) {
                const float* rl = redL[par ^ 1];
                float n = 0.f, d = 0.f;
                #pragma unroll
                for (int i = 0; i < 16; ++i) { n += rl[2 * i]; d += rl[2 * i + 1]; }
                float* pd = partials + (size_t)((iter - 1) & 7) * (2 * NBLK) + blk * 2;
                AT_STORE(&pd[0], n);
                AT_STORE(&pd[1], d);
            }
            if (iter >= 4) {  // decision for ratio_{iter-4}, identical order in every block
                const float* r3 = red32[par ^ 1];
                const float gn = (r3[0] + r3[2]) + (r3[4] + r3[6]);
                const float gd = (r3[1] + r3[3]) + (r3[5] + r3[7]);
                red40[par] = (gn < TOL2 * gd) ? 1.f : 0.f;
            }
        }

        // ---- distributed gather of ratio_{iter-3} partials (prefetched flag) ----
        float gsn = 0.f, gsd = 0.f;
        const bool chk = (iter >= 3) && (t < 256);
        if (chk) {
            const int want = iter - 2;
            while (flagv < want) {
                __builtin_amdgcn_s_sleep(2);
                flagv = AT_LOAD(&flags[t]);
            }
            asm volatile("" ::: "memory");
            const float* ps = partials + (size_t)((iter - 3) & 7) * (2 * NBLK);
            gsn = AT_LOAD(&ps[t * 2 + 0]);
            gsd = AT_LOAD(&ps[t * 2 + 1]);
        }

        // ---- a = R*S via split-bf16 MFMA, 3 independent chains ----
        f32x4 aH = {0.f, 0.f, 0.f, 0.f}, aM = {0.f, 0.f, 0.f, 0.f}, aL = {0.f, 0.f, 0.f, 0.f};
        const int arow = l15 * 260;
        #pragma unroll
        for (int s = 0; s < 8; ++s) {
            const int ab = arow + (s << 5) + (quad << 3);
            union { uint2 q[2]; short8 v; } ah, al;
            ah.q[0] = *(const uint2*)&Rhi[par][ab]; ah.q[1] = *(const uint2*)&Rhi[par][ab + 4];
            al.q[0] = *(const uint2*)&Rlo[par][ab]; al.q[1] = *(const uint2*)&Rlo[par][ab + 4];
            aH = MFMA_BF16(ah.v, Bhi[s], aH, 0, 0, 0);
            aM = MFMA_BF16(ah.v, Blo[s], aM, 0, 0, 0);
            aL = MFMA_BF16(al.v, Bhi[s], aL, 0, 0, 0);
        }

        // ---- shrink + num/den; write parity^1 ----
        float num = 0.f, den = 0.f, Nnew[4];
        #pragma unroll
        for (int i = 0; i < 4; ++i) {
            const float av = (aH[i] + aM[i]) + aL[i];
            const float v = Rold[i] + LR2 * (Gr[i] - av);
            const float n = fmaxf(v - LMDA_C, 0.f) - fmaxf(-v - LMDA_C, 0.f);
            const float d = n - Rold[i];
            num += d * d; den += Rold[i] * Rold[i];
            Nnew[i] = n;
        }
        #pragma unroll
        for (int i = 0; i < 4; ++i) {
            const int idx = ((quad << 2) + i) * 260 + colc;
            const unsigned short hb = f2bf(Nnew[i]);
            Rhi[par ^ 1][idx] = hb;
            Rlo[par ^ 1][idx] = f2bf(Nnew[i] - bf2f(hb));
        }

        // ---- local reduce -> redL[par]; gather reduce -> red32[par] ----
        #pragma unroll
        for (int off = 32; off > 0; off >>= 1) {
            num += __shfl_down(num, off, 64);
            den += __shfl_down(den, off, 64);
        }
        if (lane == 0) { redL[par][w * 2] = num; redL[par][w * 2 + 1] = den; }
        if (chk) {
            #pragma unroll
            for (int off = 32; off > 0; off >>= 1) {
                gsn += __shfl_down(gsn, off, 64);
                gsd += __shfl_down(gsd, off, 64);
            }
            if (lane == 0) { red32[par][w * 2] = gsn; red32[par][w * 2 + 1] = gsd; }
        }
        if (t < 256) flagv = AT_LOAD(&flags[t]);   // prefetch for next iter

        // ---- snapshot ring (wave-uniform switch, no rotation) ----
        const int sq = iter & 3;
        if (sq == 0)      { sn0[0]=Rold[0]; sn0[1]=Rold[1]; sn0[2]=Rold[2]; sn0[3]=Rold[3]; }
        else if (sq == 1) { sn1[0]=Rold[0]; sn1[1]=Rold[1]; sn1[2]=Rold[2]; sn1[3]=Rold[3]; }
        else if (sq == 2) { sn2[0]=Rold[0]; sn2[1]=Rold[1]; sn2[2]=Rold[2]; sn2[3]=Rold[3]; }
        else              { sn3[0]=Rold[0]; sn3[1]=Rold[1]; sn3[2]=Rold[2]; sn3[3]=Rold[3]; }
        #pragma unroll
        for (int i = 0; i < 4; ++i) Rold[i] = Nnew[i];
    }

    // ---- final R (fired at b: ratio_{b-5} < TOL -> output R_{b-4} = slot b&3) ----
    float Rf[4];
    if (!fired) {
        Rf[0] = Rold[0]; Rf[1] = Rold[1]; Rf[2] = Rold[2]; Rf[3] = Rold[3];
    } else if (fslot == 0) { Rf[0]=sn0[0]; Rf[1]=sn0[1]; Rf[2]=sn0[2]; Rf[3]=sn0[3]; }
    else if (fslot == 1)   { Rf[0]=sn1[0]; Rf[1]=sn1[1]; Rf[2]=sn1[2]; Rf[3]=sn1[3]; }
    else if (fslot == 2)   { Rf[0]=sn2[0]; Rf[1]=sn2[1]; Rf[2]=sn2[2]; Rf[3]=sn2[3]; }
    else                   { Rf[0]=sn3[0]; Rf[1]=sn3[1]; Rf[2]=sn3[2]; Rf[3]=sn3[3]; }

    #pragma unroll
    for (int i = 0; i < 4; ++i) {
        const int idx = ((quad << 2) + i) * 260 + colc;
        const unsigned short hb = f2bf(Rf[i]);
        Rhi[0][idx] = hb;
        Rlo[0][idx] = f2bf(Rf[i] - bf2f(hb));
    }
    __syncthreads();

    // ---- epilogue: out = R @ Ut via MFMA (4 tiles/wave) ----
    #pragma unroll
    for (int tt = 0; tt < 4; ++tt) {
        const int ot = tt * 16 + w;
        f32x4 aH = {0.f, 0.f, 0.f, 0.f}, aM = {0.f, 0.f, 0.f, 0.f}, aL = {0.f, 0.f, 0.f, 0.f};
        const unsigned short* ubh = UtBh + (size_t)ot * 4096 + ((size_t)lane << 3);
        const unsigned short* ubl = UtBl + (size_t)ot * 4096 + ((size_t)lane << 3);
        #pragma unroll
        for (int s = 0; s < 8; ++s) {
            const int ab = l15 * 260 + (s << 5) + (quad << 3);
            union { uint2 q[2]; short8 v; } ah, al;
            ah.q[0] = *(const uint2*)&Rhi[0][ab]; ah.q[1] = *(const uint2*)&Rhi[0][ab + 4];
            al.q[0] = *(const uint2*)&Rlo[0][ab]; al.q[1] = *(const uint2*)&Rlo[0][ab + 4];
            const short8 bh = *(const short8*)&ubh[(size_t)s << 9];
            const short8 bl = *(const short8*)&ubl[(size_t)s << 9];
            aH = MFMA_BF16(ah.v, bh, aH, 0, 0, 0);
            aM = MFMA_BF16(ah.v, bl, aM, 0, 0, 0);
            aL = MFMA_BF16(al.v, bh, aL, 0, 0, 0);
        }
        #pragma unroll
        for (int i = 0; i < 4; ++i)
            out[(size_t)(row0 + (quad << 2) + i) * PIX + (ot << 4) + l15] =
                (aH[i] + aM[i]) + aL[i];
    }
}

extern "C" void kernel_launch(void* const* d_in, const int* in_sizes, int n_in,
                              void* d_out, int out_size, void* d_ws, size_t ws_size,
                              hipStream_t stream) {
    const float* img = (const float*)d_in[0];  // [4096, 1024]
    const float* U   = (const float*)d_in[1];  // [1024, 256]
    float* out = (float*)d_out;                // [4096, 1024]

    float*          S     = (float*)d_ws;                       // 65536 f (256 KB)
    unsigned short* UGh   = (unsigned short*)((char*)d_ws + 262144);   // 512 KB
    unsigned short* UGl   = UGh + 262144;                              // 512 KB
    unsigned short* UtBh  = UGl + 262144;                              // 512 KB
    unsigned short* UtBl  = UtBh + 262144;                             // 512 KB
    float*          partials = (float*)(UtBl + 262144);                // 8*2*256 f
    int*            flags    = (int*)(partials + 8 * 2 * NBLK);        // 256 ints

    k_prep<<<336, 256, 0, stream>>>(U, S, UGh, UGl, UtBh, UtBl, flags);

    void* args[] = {(void*)&img, (void*)&S, (void*)&UGh, (void*)&UGl,
                    (void*)&UtBh, (void*)&UtBl, (void*)&out,
                    (void*)&partials, (void*)&flags};
    hipLaunchCooperativeKernel((void*)k_ista, dim3(NBLK), dim3(NTHR), args, 0, stream);
}